// Round 7
// baseline (645.698 us; speedup 1.0000x reference)
//
#include <hip/hip_runtime.h>

typedef unsigned short u16;
typedef __attribute__((ext_vector_type(8))) short short8;
typedef __attribute__((ext_vector_type(4))) float f32x4;

// ---- ws layout (bytes) ----
#define OFF_SUMS 0ul              // 6656 floats = 26624
#define OFF_WT   26624ul          // 110592*2 = 221184 : weights bf16 [dydx][192 oc][64 c]
#define OFF_ASP  247808ul         // 524288*4 = 2097152 : attn_spatial fp32 [pixel]
#define OFF_CONV 2344960ul        // 524288*192*2 = 201326592 : raw conv out bf16 [pixel][192]
// xt (NHWC bf16, 67 MB) lives in first half of d_out (fp32, 134 MB); k6 overwrites it.
// ---- S (float) offsets ----
#define S_SUM   0      // conv channel sums, 4 shadows x 192
#define S_SSQ   768    // conv channel ssq, 4 shadows x 192
#define S_SC    1536   // 192
#define S_BI    1728   // 192
#define M_A1    1920   // per (n*64+c): sum q*k        [512]
#define M_A23   2432   // sum q^2+k^2                  [512]
#define M_A45   2944   // sum q+k                      [512]
#define M_V1    3456   // sum v                        [512]
#define M_V2    3968   // sum v^2                      [512]
#define M_AV    4480   // sum asp*v                    [512]
#define M_AV2   4992   // sum asp*v^2                  [512]
#define M_A2V2  5504   // sum asp^2*v^2                [512]
#define S_ACH   6016   // attn_channel per (n,c)       [512]
#define S_SCA   6528   // final BN scale               [64]
#define S_BIA   6592   // final BN bias                [64]
#define S_NFLOAT 6656

__device__ __forceinline__ float bf2f(u16 v) {
  union { unsigned u; float f; } x; x.u = ((unsigned)v) << 16; return x.f;
}
__device__ __forceinline__ u16 f2bf(float f) {
  union { float f; unsigned u; } x; x.f = f;
  unsigned r = x.u + 0x7fffu + ((x.u >> 16) & 1u);
  return (u16)(r >> 16);
}
// v_rcp_f32: ~1 ulp approx reciprocal; error 1e-7 rel, negligible vs bf16 data path (0.4%).
__device__ __forceinline__ float frcp(float x) { return __builtin_amdgcn_rcpf(x); }
__device__ __forceinline__ float sigmoidf_(float x) { return frcp(1.f + __expf(-x)); }

// ---- DPP wave64 sum (all-VALU, zero DS ops) ----
template <int CTRL, int RMASK>
__device__ __forceinline__ float dpp_add(float x) {
  int m = __builtin_amdgcn_update_dpp(0, __builtin_bit_cast(int, x), CTRL, RMASK, 0xf, true);
  return x + __builtin_bit_cast(float, m);
}
__device__ __forceinline__ float wsum64(float x) {
  x = dpp_add<0x111, 0xf>(x);  // row_shr:1
  x = dpp_add<0x112, 0xf>(x);  // row_shr:2
  x = dpp_add<0x114, 0xf>(x);  // row_shr:4
  x = dpp_add<0x118, 0xf>(x);  // row_shr:8
  x = dpp_add<0x142, 0xa>(x);  // row_bcast:15 -> rows 1,3
  x = dpp_add<0x143, 0xc>(x);  // row_bcast:31 -> rows 2,3
  return __builtin_bit_cast(float, __builtin_amdgcn_readlane(__builtin_bit_cast(int, x), 63));
}

// ---------------- K0a: NCHW fp32 -> NHWC bf16 transpose of x (into d_out scratch) ----------------
__global__ void transpose_k(const float* __restrict__ x, u16* __restrict__ xt) {
  __shared__ u16 t[64][130];
  const int bid = blockIdx.x;
  const int wtile = bid & 1, h = (bid >> 1) & 255, n = bid >> 9;
  const int w0 = wtile << 7;
  const int tid = threadIdx.x;
  for (int i = tid; i < 8192; i += 256) {
    int c = i >> 7, w = i & 127;
    t[c][w] = f2bf(x[(((n << 6) + c) << 16) + (h << 8) + w0 + w]);
  }
  __syncthreads();
  for (int i = tid; i < 8192; i += 256) {
    int w = i >> 6, c = i & 63;
    xt[(long)((((n << 8) + h) << 8) + w0 + w) * 64 + c] = t[c][w];
  }
}

// ---------------- K0b: weight repack fp32 -> bf16 [dydx][conv*64+oc][c] ----------------
__global__ void repack_k(const float* __restrict__ wq, const float* __restrict__ wk,
                         const float* __restrict__ wv, u16* __restrict__ wt) {
  int i = blockIdx.x * 256 + threadIdx.x;
  if (i >= 110592) return;
  int conv = i / 36864, j = i % 36864;
  int oc = j / 576, r2 = j % 576, c = r2 / 9, dd = r2 % 9;
  const float* src = conv == 0 ? wq : (conv == 1 ? wk : wv);
  wt[(dd * 192 + conv * 64 + oc) * 64 + c] = f2bf(src[j]);
}

// ---------------- K1: fused QKV conv3x3 as implicit GEMM (MFMA bf16) + channel stats ----------------
// R7: occupancy lever via smaller per-wave acc. Block = 1 row x 64 w = 64 px (8192 blocks);
// wave tile = 64 px x 48 oc (mt=4, nt=3) -> acc = 48 floats (was 96). Per-CU totals (MFMA,
// LDS reads, staging bytes, B-loads) identical to R6 -- only regs/wave change.
// R6 footprint: 116 arch + 96 acc = 212 -> 2 waves/SIMD. Now ~116 + 48 = 164 <= 168
// -> 3 waves/SIMD (+50%). __launch_bounds__(256,3) pins allocator at 512/3=170 cap.
// LDS: 3 rows x 66 px x 64 ch = 25344 B, R2-verified conflict-free XOR swizzle.
__global__ __launch_bounds__(256, 3) void conv_k(const u16* __restrict__ xt,
                                                 const u16* __restrict__ wt,
                                                 u16* __restrict__ conv,
                                                 float* __restrict__ S) {
  __shared__ u16 lx[3 * 4224];  // 3 rows * 66 px * 64 ch = 25344 B
  const int bid = blockIdx.x;
  const int wb = bid & 3, h = (bid >> 2) & 255, n = bid >> 10;
  const int w0 = wb << 6;
  const int tid = threadIdx.x;
  // stage 3 input rows (h-1 .. h+1) x 66 px (w0-1 .. w0+64) x 64 ch
  for (int g = tid; g < 1584; g += 256) {
    int row = g / 528;
    int r2 = g - row * 528;
    int px = r2 >> 3, cg = r2 & 7;
    int hs = h + row - 1, wsr = w0 + px - 1;
    uint4 val = make_uint4(0u, 0u, 0u, 0u);
    if ((unsigned)hs < 256u && (unsigned)wsr < 256u)
      val = *(const uint4*)(xt + (long)((((n << 8) + hs) << 8) + wsr) * 64 + (cg << 3));
    int idx = ((px << 6) + (cg << 3)) ^ ((px & 7) << 3);
    *(uint4*)(&lx[row * 4224 + idx]) = val;
  }
  __syncthreads();
  const int lane = tid & 63, wave = tid >> 6;
  const int quad = lane >> 4, l15 = lane & 15;
  f32x4 acc[3][4];
#pragma unroll
  for (int a = 0; a < 3; ++a)
#pragma unroll
    for (int b = 0; b < 4; ++b) acc[a][b] = (f32x4){0.f, 0.f, 0.f, 0.f};

#pragma unroll
  for (int dy = 0; dy < 3; ++dy) {
#pragma unroll
    for (int dx = 0; dx < 3; ++dx) {
      const u16* wp = wt + (dy * 3 + dx) * 12288;
      short8 bfr[3][2];
#pragma unroll
      for (int nt = 0; nt < 3; ++nt)
#pragma unroll
        for (int kc = 0; kc < 2; ++kc)
          bfr[nt][kc] = *(const short8*)(wp + ((wave * 3 + nt) * 16 + l15) * 64 + kc * 32 + quad * 8);
#pragma unroll
      for (int kc = 0; kc < 2; ++kc) {
        short8 afr[4];
#pragma unroll
        for (int mt = 0; mt < 4; ++mt) {
          const int wloc = mt * 16 + l15 + dx;  // staged col (0..65)
          int idx = ((wloc << 6) + (kc << 5) + (quad << 3)) ^ ((wloc & 7) << 3);
          afr[mt] = *(const short8*)(&lx[dy * 4224 + idx]);
        }
#pragma unroll
        for (int mt = 0; mt < 4; ++mt)
#pragma unroll
          for (int nt = 0; nt < 3; ++nt)
            acc[nt][mt] = __builtin_amdgcn_mfma_f32_16x16x32_bf16(afr[mt], bfr[nt][kc], acc[nt][mt], 0, 0, 0);
      }
    }
  }
  // epilogue: D row = quad*4+r (pixel), col = l15 (oc); store bf16 [pixel][192]
  const long pix0 = (long)bid * 64;
#pragma unroll
  for (int nt = 0; nt < 3; ++nt) {
    const int oc = (wave * 3 + nt) * 16 + l15;
#pragma unroll
    for (int mt = 0; mt < 4; ++mt) {
      const long pr = pix0 + mt * 16 + quad * 4;
#pragma unroll
      for (int r = 0; r < 4; ++r)
        conv[(pr + r) * 192 + oc] = f2bf(acc[nt][mt][r]);
    }
  }
  // fused per-channel stats: lane's 16 pixels -> quad-reduce (64 px) -> shadowed atomics
  const int sh = (bid & 3) * 192;
#pragma unroll
  for (int nt = 0; nt < 3; ++nt) {
    float s = 0.f, ss = 0.f;
#pragma unroll
    for (int mt = 0; mt < 4; ++mt)
#pragma unroll
      for (int r = 0; r < 4; ++r) {
        float x = acc[nt][mt][r];
        s += x; ss += x * x;
      }
    s += __shfl_xor(s, 16); ss += __shfl_xor(ss, 16);
    s += __shfl_xor(s, 32); ss += __shfl_xor(ss, 32);
    if (lane < 16) {
      const int oc = (wave * 3 + nt) * 16 + l15;
      atomicAdd(&S[S_SUM + sh + oc], s);
      atomicAdd(&S[S_SSQ + sh + oc], ss);
    }
  }
}

// ---------------- K2b: BN scale/bias for q,k,v ----------------
__global__ void bnparam_k(float* __restrict__ S, const float* gq, const float* bq, const float* gk,
                          const float* bk, const float* gv, const float* bv) {
  int t = threadIdx.x;  // 192
  int cv = t >> 6, c = t & 63;
  float g = cv == 0 ? gq[c] : (cv == 1 ? gk[c] : gv[c]);
  float b = cv == 0 ? bq[c] : (cv == 1 ? bk[c] : bv[c]);
  float sm = 0.f, sq = 0.f;
#pragma unroll
  for (int sh = 0; sh < 4; ++sh) { sm += S[S_SUM + sh * 192 + t]; sq += S[S_SSQ + sh * 192 + t]; }
  const float inv = 1.f / 524288.f;
  float mean = sm * inv;
  float var = sq * inv - mean * mean;
  float rstd = rsqrtf(var + 1e-5f);
  float sc = g * rstd;
  S[S_SC + t] = sc;
  S[S_BI + t] = b - mean * sc;
}

// ---------------- K3: BN+sigmoid q,k,v; asp per pixel; 8 moments per (n,c) ----------------
// DPP channel reduce (R6): 0 DS ops in the hot loop.
__global__ void k3_k(const u16* __restrict__ conv, float* __restrict__ S, float* __restrict__ asp) {
  __shared__ float red[4][8][64];
  const int tid = threadIdx.x, lane = tid & 63, wave = tid >> 6;
  const int bid = blockIdx.x;          // 4096 blocks x 128 px
  const int n = bid >> 9;
  const long p0 = (long)bid * 128 + wave * 32;
  const float sq = S[S_SC + lane], bq = S[S_BI + lane];
  const float sk = S[S_SC + 64 + lane], bk = S[S_BI + 64 + lane];
  const float sv = S[S_SC + 128 + lane], bv = S[S_BI + 128 + lane];
  float A1 = 0.f, A23 = 0.f, A45 = 0.f, V1 = 0.f, V2 = 0.f, AV = 0.f, AV2 = 0.f, A2V2 = 0.f;
  float myasp = 0.f;
#pragma unroll 4
  for (int i = 0; i < 32; ++i) {
    const u16* row = conv + (p0 + i) * 192;
    float q = sigmoidf_(bf2f(row[lane]) * sq + bq);
    float k = sigmoidf_(bf2f(row[64 + lane]) * sk + bk);
    float v = sigmoidf_(bf2f(row[128 + lane]) * sv + bv);
    float p1 = q * k, p23 = q * q + k * k, p45 = q + k;
    A1 += p1; A23 += p23; A45 += p45;
    float s1 = wsum64(p1);
    float s23 = wsum64(p23);
    float s45 = wsum64(p45);
    const float sm = 1e-5f;
    float t1 = (s1 + sm) * frcp(s23 - s1 + sm);
    float t2 = (64.f - s45 + s1 + sm) * frcp(64.f - s45 + s23 - s1 + sm);
    float a = 0.5f * (t1 + t2);
    if (i == (lane & 31)) myasp = a;
    float av = a * v;
    V1 += v; V2 += v * v; AV += av; AV2 += av * v; A2V2 += av * av;
  }
  if (lane < 32) asp[p0 + lane] = myasp;
  red[wave][0][lane] = A1;  red[wave][1][lane] = A23; red[wave][2][lane] = A45;
  red[wave][3][lane] = V1;  red[wave][4][lane] = V2;  red[wave][5][lane] = AV;
  red[wave][6][lane] = AV2; red[wave][7][lane] = A2V2;
  __syncthreads();
  if (tid < 64) {
    const int mb[8] = {M_A1, M_A23, M_A45, M_V1, M_V2, M_AV, M_AV2, M_A2V2};
#pragma unroll
    for (int m = 0; m < 8; ++m) {
      float t = red[0][m][tid] + red[1][m][tid] + red[2][m][tid] + red[3][m][tid];
      atomicAdd(&S[mb[m] + n * 64 + tid], t);
    }
  }
}

// ---------------- K4: attn_channel per (n,c) + final BN params ----------------
__global__ void k4_k(float* __restrict__ S, const float* gn, const float* bn_) {
  __shared__ float r1[512], r2[512];
  const int t = threadIdx.x;  // 512 = (n,c)
  float A1 = S[M_A1 + t], A23 = S[M_A23 + t], A45 = S[M_A45 + t];
  const float sm = 1e-5f, cnt = 65536.f;
  float t1 = (A1 + sm) / (A23 - A1 + sm);
  float t2 = (cnt - A45 + A1 + sm) / (cnt - A45 + A23 - A1 + sm);
  float ach = 0.5f * (t1 + t2);
  S[S_ACH + t] = ach;
  r1[t] = 0.5f * (S[M_AV + t] + ach * S[M_V1 + t]);
  r2[t] = 0.25f * (S[M_A2V2 + t] + 2.f * ach * S[M_AV2 + t] + ach * ach * S[M_V2 + t]);
  __syncthreads();
  if (t < 64) {
    float s = 0.f, ss = 0.f;
#pragma unroll
    for (int n = 0; n < 8; ++n) { s += r1[n * 64 + t]; ss += r2[n * 64 + t]; }
    const float inv = 1.f / 524288.f;
    float mean = s * inv;
    float var = ss * inv - mean * mean;
    float rstd = rsqrtf(var + 1e-5f);
    float sc = gn[t] * rstd;
    S[S_SCA + t] = sc;
    S[S_BIA + t] = bn_[t] - mean * sc;
  }
}

// ---------------- K6: attention -> final BN -> NCHW fp32 out (LDS transpose) ----------------
__global__ void k6_k(const u16* __restrict__ conv, const float* __restrict__ S,
                     const float* __restrict__ asp, float* __restrict__ out) {
  __shared__ float t[128][65];
  const int tid = threadIdx.x, lane = tid & 63, wave = tid >> 6;
  const int n = blockIdx.x >> 9;
  const int hw0 = (blockIdx.x & 511) << 7;
  const long P0 = (long)blockIdx.x * 128;
  const float sv = S[S_SC + 128 + lane], bv = S[S_BI + 128 + lane];
  const float av = S[S_ACH + n * 64 + lane];
  const float sA = S[S_SCA + lane], bA = S[S_BIA + lane];
  for (int i = wave; i < 128; i += 4) {
    const long p = P0 + i;
    float v = sigmoidf_(bf2f(conv[p * 192 + 128 + lane]) * sv + bv);
    float att = 0.5f * (asp[p] + av) * v;
    t[i][lane] = att * sA + bA;
  }
  __syncthreads();
  const int c = tid >> 2, sub = tid & 3;
  const long plane = ((long)((n << 6) + c)) << 16;
  for (int i = 0; i < 8; ++i) {
    const int pst = (i * 4 + sub) << 2;
    f32x4 vbuf;
#pragma unroll
    for (int j = 0; j < 4; ++j) vbuf[j] = t[pst + j][c];
    *(f32x4*)(&out[plane + hw0 + pst]) = vbuf;
  }
}

extern "C" void kernel_launch(void* const* d_in, const int* in_sizes, int n_in,
                              void* d_out, int out_size, void* d_ws, size_t ws_size,
                              hipStream_t stream) {
  (void)in_sizes; (void)n_in; (void)out_size; (void)ws_size;
  const float* x  = (const float*)d_in[0];
  const float* wq = (const float*)d_in[1];
  const float* gq = (const float*)d_in[2];
  const float* bq = (const float*)d_in[3];
  const float* wk = (const float*)d_in[4];
  const float* gk = (const float*)d_in[5];
  const float* bk = (const float*)d_in[6];
  const float* wv = (const float*)d_in[7];
  const float* gv = (const float*)d_in[8];
  const float* bv = (const float*)d_in[9];
  const float* gn = (const float*)d_in[10];
  const float* bn_ = (const float*)d_in[11];
  char* ws = (char*)d_ws;
  float* S   = (float*)(ws + OFF_SUMS);
  u16* wt    = (u16*)(ws + OFF_WT);
  float* asp = (float*)(ws + OFF_ASP);
  u16* conv  = (u16*)(ws + OFF_CONV);
  float* out = (float*)d_out;
  u16* xt  = (u16*)d_out;  // bf16 NHWC scratch in first half of fp32 out; overwritten by k6_k

  (void)hipMemsetAsync(S, 0, S_NFLOAT * 4, stream);
  transpose_k<<<4096, 256, 0, stream>>>(x, xt);
  repack_k<<<432, 256, 0, stream>>>(wq, wk, wv, wt);
  conv_k<<<8192, 256, 0, stream>>>(xt, wt, conv, S);
  bnparam_k<<<1, 192, 0, stream>>>(S, gq, bq, gk, bk, gv, bv);
  k3_k<<<4096, 256, 0, stream>>>(conv, S, asp);
  k4_k<<<1, 512, 0, stream>>>(S, gn, bn_);
  k6_k<<<4096, 256, 0, stream>>>(conv, S, asp, out);
}

// Round 8
// 552.584 us; speedup vs baseline: 1.1685x; 1.1685x over previous
//
#include <hip/hip_runtime.h>

typedef unsigned short u16;
typedef __attribute__((ext_vector_type(8))) short short8;
typedef __attribute__((ext_vector_type(4))) float f32x4;
typedef __attribute__((ext_vector_type(16))) float f32x16;

// ---- ws layout (bytes) ----
#define OFF_SUMS 0ul              // 6656 floats = 26624
#define OFF_WT   26624ul          // 110592*2 = 221184 : weights bf16, fragment-major (see repack_k)
#define OFF_ASP  247808ul         // 524288*4 = 2097152 : attn_spatial fp32 [pixel]
#define OFF_CONV 2344960ul        // 524288*192*2 = 201326592 : raw conv out bf16 [pixel][192]
// xt (NHWC bf16, 67 MB) lives in first half of d_out (fp32, 134 MB); k6 overwrites it.
// ---- S (float) offsets ----
#define S_SUM   0      // conv channel sums, 4 shadows x 192
#define S_SSQ   768    // conv channel ssq, 4 shadows x 192
#define S_SC    1536   // 192
#define S_BI    1728   // 192
#define M_A1    1920   // per (n*64+c): sum q*k        [512]
#define M_A23   2432   // sum q^2+k^2                  [512]
#define M_A45   2944   // sum q+k                      [512]
#define M_V1    3456   // sum v                        [512]
#define M_V2    3968   // sum v^2                      [512]
#define M_AV    4480   // sum asp*v                    [512]
#define M_AV2   4992   // sum asp*v^2                  [512]
#define M_A2V2  5504   // sum asp^2*v^2                [512]
#define S_ACH   6016   // attn_channel per (n,c)       [512]
#define S_SCA   6528   // final BN scale               [64]
#define S_BIA   6592   // final BN bias                [64]
#define S_NFLOAT 6656

__device__ __forceinline__ float bf2f(u16 v) {
  union { unsigned u; float f; } x; x.u = ((unsigned)v) << 16; return x.f;
}
__device__ __forceinline__ u16 f2bf(float f) {
  union { float f; unsigned u; } x; x.f = f;
  unsigned r = x.u + 0x7fffu + ((x.u >> 16) & 1u);
  return (u16)(r >> 16);
}
// v_rcp_f32: ~1 ulp approx reciprocal; error 1e-7 rel, negligible vs bf16 data path (0.4%).
__device__ __forceinline__ float frcp(float x) { return __builtin_amdgcn_rcpf(x); }
__device__ __forceinline__ float sigmoidf_(float x) { return frcp(1.f + __expf(-x)); }

// ---- DPP wave64 sum (all-VALU, zero DS ops) ----
template <int CTRL, int RMASK>
__device__ __forceinline__ float dpp_add(float x) {
  int m = __builtin_amdgcn_update_dpp(0, __builtin_bit_cast(int, x), CTRL, RMASK, 0xf, true);
  return x + __builtin_bit_cast(float, m);
}
__device__ __forceinline__ float wsum64(float x) {
  x = dpp_add<0x111, 0xf>(x);  // row_shr:1
  x = dpp_add<0x112, 0xf>(x);  // row_shr:2
  x = dpp_add<0x114, 0xf>(x);  // row_shr:4
  x = dpp_add<0x118, 0xf>(x);  // row_shr:8
  x = dpp_add<0x142, 0xa>(x);  // row_bcast:15 -> rows 1,3
  x = dpp_add<0x143, 0xc>(x);  // row_bcast:31 -> rows 2,3
  return __builtin_bit_cast(float, __builtin_amdgcn_readlane(__builtin_bit_cast(int, x), 63));
}

// ---------------- K0a: NCHW fp32 -> NHWC bf16 transpose of x (into d_out scratch) ----------------
__global__ void transpose_k(const float* __restrict__ x, u16* __restrict__ xt) {
  __shared__ u16 t[64][130];
  const int bid = blockIdx.x;
  const int wtile = bid & 1, h = (bid >> 1) & 255, n = bid >> 9;
  const int w0 = wtile << 7;
  const int tid = threadIdx.x;
  for (int i = tid; i < 8192; i += 256) {
    int c = i >> 7, w = i & 127;
    t[c][w] = f2bf(x[(((n << 6) + c) << 16) + (h << 8) + w0 + w]);
  }
  __syncthreads();
  for (int i = tid; i < 8192; i += 256) {
    int w = i >> 6, c = i & 63;
    xt[(long)((((n << 8) + h) << 8) + w0 + w) * 64 + c] = t[c][w];
  }
}

// ---------------- K0b: weight repack fp32 -> bf16, fragment-major for 32x32x16 MFMA ----------------
// Layout: [dydx 9][ocg 6][kc 4][lane 64][j 8]  (elements; 16B per lane per fragment).
// Fragment (dydx, ocg, kc): lane l, elem j = W[oc = ocg*32 + (l&31)][ch = kc*16 + (l>>5)*8 + j]
// -> conv_k B-loads are lane*16B contiguous (1KB/instr fully coalesced).
__global__ void repack_k(const float* __restrict__ wq, const float* __restrict__ wk,
                         const float* __restrict__ wv, u16* __restrict__ wt) {
  int i = blockIdx.x * 256 + threadIdx.x;
  if (i >= 110592) return;
  int j = i & 7, l = (i >> 3) & 63, kc = (i >> 9) & 3;
  int t2 = i >> 11;              // dydx*6 + ocg
  int ocg = t2 % 6, dydx = t2 / 6;
  int oc = ocg * 32 + (l & 31);
  int ch = kc * 16 + (l >> 5) * 8 + j;
  int cs = oc >> 6, ol = oc & 63;
  const float* src = cs == 0 ? wq : (cs == 1 ? wk : wv);
  wt[i] = f2bf(src[(ol * 64 + ch) * 9 + dydx]);
}

// ---------------- K1: fused QKV conv3x3 as implicit GEMM (MFMA bf16) + channel stats ----------------
// R8: same R6 block geometry (1 row x 128 w, 4 waves, identical swizzled staging) but
// mfma_f32_32x32x16_bf16: a 16B A-fragment feeds 16K MACs (vs 8K for 16x16x32), so block-level
// A LDS traffic halves (each A elem read by 2 waves not 4: 72 b128/wave vs 144) and the 32x32
// pipe is ~15% faster (2382 vs 2075 TF ubench). Wave tile: 64 px (wm) x 96 oc (wn), 2mt x 3nt,
// acc = 96 f32 (unchanged -> still 2 waves/SIMD; R7 proved occupancy isn't the lever).
// Fragment maps: A row=lane&31 (px), k=(lane>>5)*8+j; B col=lane&31 (oc), k=(lane>>5)*8+j
// (pre-swizzled by repack_k); C col=lane&31 (oc), row=(reg&3)+8*(reg>>2)+4*(lane>>5) (px)
// [guide-verified m74/m101].
__global__ __launch_bounds__(256, 2) void conv_k(const u16* __restrict__ xt,
                                                 const u16* __restrict__ wt,
                                                 u16* __restrict__ conv,
                                                 float* __restrict__ S) {
  __shared__ u16 lx[3 * 8320];  // 3 rows * 130 px * 64 ch = 49920 B
  const int bid = blockIdx.x;
  const int wtile = bid & 1, h = (bid >> 1) & 255, n = bid >> 9;
  const int w0 = wtile << 7;
  const int tid = threadIdx.x;
  for (int g = tid; g < 3120; g += 256) {
    int row = g / 1040;
    int r2 = g - row * 1040;
    int w = r2 >> 3, cg = r2 & 7;
    int hs = h + row - 1, wsr = w0 + w - 1;
    uint4 val = make_uint4(0u, 0u, 0u, 0u);
    if ((unsigned)hs < 256u && (unsigned)wsr < 256u)
      val = *(const uint4*)(xt + (long)((((n << 8) + hs) << 8) + wsr) * 64 + (cg << 3));
    int idx = ((w << 6) + (cg << 3)) ^ ((w & 7) << 3);
    *(uint4*)(&lx[row * 8320 + idx]) = val;
  }
  __syncthreads();
  const int lane = tid & 63, wave = tid >> 6;
  const int l31 = lane & 31, half = lane >> 5;
  const int wm = wave & 1, wn = wave >> 1;  // wm: px half (64), wn: oc group (96)
  f32x16 acc[3][2];
#pragma unroll
  for (int a = 0; a < 3; ++a)
#pragma unroll
    for (int b = 0; b < 2; ++b)
#pragma unroll
      for (int e = 0; e < 16; ++e) acc[a][b][e] = 0.f;

#pragma unroll
  for (int dy = 0; dy < 3; ++dy) {
#pragma unroll
    for (int dx = 0; dx < 3; ++dx) {
      const u16* wp = wt + (dy * 3 + dx) * 12288;
      short8 bfr[3][4];
#pragma unroll
      for (int nt = 0; nt < 3; ++nt)
#pragma unroll
        for (int kc = 0; kc < 4; ++kc)
          bfr[nt][kc] = *(const short8*)(wp + ((wn * 3 + nt) * 4 + kc) * 512 + lane * 8);
#pragma unroll
      for (int kc = 0; kc < 4; ++kc) {
        short8 afr[2];
#pragma unroll
        for (int mt = 0; mt < 2; ++mt) {
          const int px = wm * 64 + mt * 32 + l31 + dx;       // staged col (0..129)
          const int chb = kc * 16 + half * 8;                // k-slice base channel
          int idx = ((px << 6) + chb) ^ ((px & 7) << 3);
          afr[mt] = *(const short8*)(&lx[dy * 8320 + idx]);
        }
#pragma unroll
        for (int mt = 0; mt < 2; ++mt)
#pragma unroll
          for (int nt = 0; nt < 3; ++nt)
            acc[nt][mt] = __builtin_amdgcn_mfma_f32_32x32x16_bf16(afr[mt], bfr[nt][kc], acc[nt][mt], 0, 0, 0);
      }
    }
  }
  // epilogue: C col = l31 (oc), row = (r&3) + 8*(r>>2) + 4*half (px); store bf16 [pixel][192]
  const long pix0 = (long)bid * 128 + wm * 64;
#pragma unroll
  for (int nt = 0; nt < 3; ++nt) {
    const int oc = wn * 96 + nt * 32 + l31;
#pragma unroll
    for (int mt = 0; mt < 2; ++mt) {
      const long pxb = pix0 + mt * 32 + half * 4;
#pragma unroll
      for (int rq = 0; rq < 4; ++rq)
#pragma unroll
        for (int rr = 0; rr < 4; ++rr) {
          const long px = pxb + rr + 8 * rq;
          conv[px * 192 + oc] = f2bf(acc[nt][mt][rq * 4 + rr]);
        }
    }
  }
  // fused per-channel stats: lane holds one oc column (32 rows x 2 mt after half-fold)
  const int sh = (bid & 3) * 192;
#pragma unroll
  for (int nt = 0; nt < 3; ++nt) {
    float s = 0.f, ss = 0.f;
#pragma unroll
    for (int mt = 0; mt < 2; ++mt)
#pragma unroll
      for (int r = 0; r < 16; ++r) {
        float x = acc[nt][mt][r];
        s += x; ss += x * x;
      }
    s += __shfl_xor(s, 32); ss += __shfl_xor(ss, 32);
    if (lane < 32) {
      const int oc = wn * 96 + nt * 32 + lane;
      atomicAdd(&S[S_SUM + sh + oc], s);
      atomicAdd(&S[S_SSQ + sh + oc], ss);
    }
  }
}

// ---------------- K2b: BN scale/bias for q,k,v ----------------
__global__ void bnparam_k(float* __restrict__ S, const float* gq, const float* bq, const float* gk,
                          const float* bk, const float* gv, const float* bv) {
  int t = threadIdx.x;  // 192
  int cv = t >> 6, c = t & 63;
  float g = cv == 0 ? gq[c] : (cv == 1 ? gk[c] : gv[c]);
  float b = cv == 0 ? bq[c] : (cv == 1 ? bk[c] : bv[c]);
  float sm = 0.f, sq = 0.f;
#pragma unroll
  for (int sh = 0; sh < 4; ++sh) { sm += S[S_SUM + sh * 192 + t]; sq += S[S_SSQ + sh * 192 + t]; }
  const float inv = 1.f / 524288.f;
  float mean = sm * inv;
  float var = sq * inv - mean * mean;
  float rstd = rsqrtf(var + 1e-5f);
  float sc = g * rstd;
  S[S_SC + t] = sc;
  S[S_BI + t] = b - mean * sc;
}

// ---------------- K3: BN+sigmoid q,k,v; asp per pixel; 8 moments per (n,c) ----------------
// DPP channel reduce (R6): 0 DS ops in the hot loop.
__global__ void k3_k(const u16* __restrict__ conv, float* __restrict__ S, float* __restrict__ asp) {
  __shared__ float red[4][8][64];
  const int tid = threadIdx.x, lane = tid & 63, wave = tid >> 6;
  const int bid = blockIdx.x;          // 4096 blocks x 128 px
  const int n = bid >> 9;
  const long p0 = (long)bid * 128 + wave * 32;
  const float sq = S[S_SC + lane], bq = S[S_BI + lane];
  const float sk = S[S_SC + 64 + lane], bk = S[S_BI + 64 + lane];
  const float sv = S[S_SC + 128 + lane], bv = S[S_BI + 128 + lane];
  float A1 = 0.f, A23 = 0.f, A45 = 0.f, V1 = 0.f, V2 = 0.f, AV = 0.f, AV2 = 0.f, A2V2 = 0.f;
  float myasp = 0.f;
#pragma unroll 4
  for (int i = 0; i < 32; ++i) {
    const u16* row = conv + (p0 + i) * 192;
    float q = sigmoidf_(bf2f(row[lane]) * sq + bq);
    float k = sigmoidf_(bf2f(row[64 + lane]) * sk + bk);
    float v = sigmoidf_(bf2f(row[128 + lane]) * sv + bv);
    float p1 = q * k, p23 = q * q + k * k, p45 = q + k;
    A1 += p1; A23 += p23; A45 += p45;
    float s1 = wsum64(p1);
    float s23 = wsum64(p23);
    float s45 = wsum64(p45);
    const float sm = 1e-5f;
    float t1 = (s1 + sm) * frcp(s23 - s1 + sm);
    float t2 = (64.f - s45 + s1 + sm) * frcp(64.f - s45 + s23 - s1 + sm);
    float a = 0.5f * (t1 + t2);
    if (i == (lane & 31)) myasp = a;
    float av = a * v;
    V1 += v; V2 += v * v; AV += av; AV2 += av * v; A2V2 += av * av;
  }
  if (lane < 32) asp[p0 + lane] = myasp;
  red[wave][0][lane] = A1;  red[wave][1][lane] = A23; red[wave][2][lane] = A45;
  red[wave][3][lane] = V1;  red[wave][4][lane] = V2;  red[wave][5][lane] = AV;
  red[wave][6][lane] = AV2; red[wave][7][lane] = A2V2;
  __syncthreads();
  if (tid < 64) {
    const int mb[8] = {M_A1, M_A23, M_A45, M_V1, M_V2, M_AV, M_AV2, M_A2V2};
#pragma unroll
    for (int m = 0; m < 8; ++m) {
      float t = red[0][m][tid] + red[1][m][tid] + red[2][m][tid] + red[3][m][tid];
      atomicAdd(&S[mb[m] + n * 64 + tid], t);
    }
  }
}

// ---------------- K4: attn_channel per (n,c) + final BN params ----------------
__global__ void k4_k(float* __restrict__ S, const float* gn, const float* bn_) {
  __shared__ float r1[512], r2[512];
  const int t = threadIdx.x;  // 512 = (n,c)
  float A1 = S[M_A1 + t], A23 = S[M_A23 + t], A45 = S[M_A45 + t];
  const float sm = 1e-5f, cnt = 65536.f;
  float t1 = (A1 + sm) / (A23 - A1 + sm);
  float t2 = (cnt - A45 + A1 + sm) / (cnt - A45 + A23 - A1 + sm);
  float ach = 0.5f * (t1 + t2);
  S[S_ACH + t] = ach;
  r1[t] = 0.5f * (S[M_AV + t] + ach * S[M_V1 + t]);
  r2[t] = 0.25f * (S[M_A2V2 + t] + 2.f * ach * S[M_AV2 + t] + ach * ach * S[M_V2 + t]);
  __syncthreads();
  if (t < 64) {
    float s = 0.f, ss = 0.f;
#pragma unroll
    for (int n = 0; n < 8; ++n) { s += r1[n * 64 + t]; ss += r2[n * 64 + t]; }
    const float inv = 1.f / 524288.f;
    float mean = s * inv;
    float var = ss * inv - mean * mean;
    float rstd = rsqrtf(var + 1e-5f);
    float sc = gn[t] * rstd;
    S[S_SCA + t] = sc;
    S[S_BIA + t] = bn_[t] - mean * sc;
  }
}

// ---------------- K6: attention -> final BN -> NCHW fp32 out (LDS transpose) ----------------
__global__ void k6_k(const u16* __restrict__ conv, const float* __restrict__ S,
                     const float* __restrict__ asp, float* __restrict__ out) {
  __shared__ float t[128][65];
  const int tid = threadIdx.x, lane = tid & 63, wave = tid >> 6;
  const int n = blockIdx.x >> 9;
  const int hw0 = (blockIdx.x & 511) << 7;
  const long P0 = (long)blockIdx.x * 128;
  const float sv = S[S_SC + 128 + lane], bv = S[S_BI + 128 + lane];
  const float av = S[S_ACH + n * 64 + lane];
  const float sA = S[S_SCA + lane], bA = S[S_BIA + lane];
  for (int i = wave; i < 128; i += 4) {
    const long p = P0 + i;
    float v = sigmoidf_(bf2f(conv[p * 192 + 128 + lane]) * sv + bv);
    float att = 0.5f * (asp[p] + av) * v;
    t[i][lane] = att * sA + bA;
  }
  __syncthreads();
  const int c = tid >> 2, sub = tid & 3;
  const long plane = ((long)((n << 6) + c)) << 16;
  for (int i = 0; i < 8; ++i) {
    const int pst = (i * 4 + sub) << 2;
    f32x4 vbuf;
#pragma unroll
    for (int j = 0; j < 4; ++j) vbuf[j] = t[pst + j][c];
    *(f32x4*)(&out[plane + hw0 + pst]) = vbuf;
  }
}

extern "C" void kernel_launch(void* const* d_in, const int* in_sizes, int n_in,
                              void* d_out, int out_size, void* d_ws, size_t ws_size,
                              hipStream_t stream) {
  (void)in_sizes; (void)n_in; (void)out_size; (void)ws_size;
  const float* x  = (const float*)d_in[0];
  const float* wq = (const float*)d_in[1];
  const float* gq = (const float*)d_in[2];
  const float* bq = (const float*)d_in[3];
  const float* wk = (const float*)d_in[4];
  const float* gk = (const float*)d_in[5];
  const float* bk = (const float*)d_in[6];
  const float* wv = (const float*)d_in[7];
  const float* gv = (const float*)d_in[8];
  const float* bv = (const float*)d_in[9];
  const float* gn = (const float*)d_in[10];
  const float* bn_ = (const float*)d_in[11];
  char* ws = (char*)d_ws;
  float* S   = (float*)(ws + OFF_SUMS);
  u16* wt    = (u16*)(ws + OFF_WT);
  float* asp = (float*)(ws + OFF_ASP);
  u16* conv  = (u16*)(ws + OFF_CONV);
  float* out = (float*)d_out;
  u16* xt  = (u16*)d_out;  // bf16 NHWC scratch in first half of fp32 out; overwritten by k6_k

  (void)hipMemsetAsync(S, 0, S_NFLOAT * 4, stream);
  transpose_k<<<4096, 256, 0, stream>>>(x, xt);
  repack_k<<<432, 256, 0, stream>>>(wq, wk, wv, wt);
  conv_k<<<4096, 256, 0, stream>>>(xt, wt, conv, S);
  bnparam_k<<<1, 192, 0, stream>>>(S, gq, bq, gk, bk, gv, bv);
  k3_k<<<4096, 256, 0, stream>>>(conv, S, asp);
  k4_k<<<1, 512, 0, stream>>>(S, gn, bn_);
  k6_k<<<4096, 256, 0, stream>>>(conv, S, asp, out);
}

// Round 9
// 551.242 us; speedup vs baseline: 1.1714x; 1.0024x over previous
//
#include <hip/hip_runtime.h>

typedef unsigned short u16;
typedef __attribute__((ext_vector_type(8))) short short8;
typedef __attribute__((ext_vector_type(4))) float f32x4;
typedef __attribute__((ext_vector_type(16))) float f32x16;

// ---- ws layout (bytes) ----
#define OFF_SUMS 0ul              // 6656 floats = 26624
#define OFF_WT   26624ul          // 110592*2 = 221184 : weights bf16, fragment-major (see tr_k)
#define OFF_ASP  247808ul         // 524288*4 = 2097152 : attn_spatial fp32 [pixel]
#define OFF_CONV 2344960ul        // 524288*192*2 = 201326592 : raw conv out bf16 [pixel][192]
// xt (NHWC bf16, 67 MB) lives in first half of d_out (fp32, 134 MB); k6 overwrites it.
// ---- S (float) offsets ----
#define S_SUM   0      // conv channel sums, 4 shadows x 192
#define S_SSQ   768    // conv channel ssq, 4 shadows x 192
#define M_A1    1920   // per (n*64+c): sum q*k        [512]
#define M_A23   2432   // sum q^2+k^2                  [512]
#define M_A45   2944   // sum q+k                      [512]
#define M_V1    3456   // sum v                        [512]
#define M_V2    3968   // sum v^2                      [512]
#define M_AV    4480   // sum asp*v                    [512]
#define M_AV2   4992   // sum asp*v^2                  [512]
#define M_A2V2  5504   // sum asp^2*v^2                [512]
#define S_NFLOAT 6656

__device__ __forceinline__ float bf2f(u16 v) {
  union { unsigned u; float f; } x; x.u = ((unsigned)v) << 16; return x.f;
}
__device__ __forceinline__ u16 f2bf(float f) {
  union { float f; unsigned u; } x; x.f = f;
  unsigned r = x.u + 0x7fffu + ((x.u >> 16) & 1u);
  return (u16)(r >> 16);
}
// v_rcp_f32: ~1 ulp approx reciprocal; error 1e-7 rel, negligible vs bf16 data path (0.4%).
__device__ __forceinline__ float frcp(float x) { return __builtin_amdgcn_rcpf(x); }
__device__ __forceinline__ float sigmoidf_(float x) { return frcp(1.f + __expf(-x)); }

// ---- DPP wave64 sum (all-VALU, zero DS ops) ----
template <int CTRL, int RMASK>
__device__ __forceinline__ float dpp_add(float x) {
  int m = __builtin_amdgcn_update_dpp(0, __builtin_bit_cast(int, x), CTRL, RMASK, 0xf, true);
  return x + __builtin_bit_cast(float, m);
}
__device__ __forceinline__ float wsum64(float x) {
  x = dpp_add<0x111, 0xf>(x);  // row_shr:1
  x = dpp_add<0x112, 0xf>(x);  // row_shr:2
  x = dpp_add<0x114, 0xf>(x);  // row_shr:4
  x = dpp_add<0x118, 0xf>(x);  // row_shr:8
  x = dpp_add<0x142, 0xa>(x);  // row_bcast:15 -> rows 1,3
  x = dpp_add<0x143, 0xc>(x);  // row_bcast:31 -> rows 2,3
  return __builtin_bit_cast(float, __builtin_amdgcn_readlane(__builtin_bit_cast(int, x), 63));
}

// ---------------- K0: fused transpose (blocks 0..4095) + weight repack (blocks 4096..) ----------
// Transpose vectorized (R9): float4 x-reads (8/thread, was 32 scalar), b32 LDS writes,
// dwordx4 xt stores (4/thread, was 32 scalar 2B). VMEM instrs 64 -> 12 per thread.
// Repack: fragment-major for 32x32x16 MFMA: [dydx 9][ocg 6][kc 4][lane 64][j 8];
// fragment (dydx,ocg,kc): lane l elem j = W[oc=ocg*32+(l&31)][ch=kc*16+(l>>5)*8+j].
__global__ void tr_k(const float* __restrict__ x, u16* __restrict__ xt,
                     const float* __restrict__ wq, const float* __restrict__ wk,
                     const float* __restrict__ wv, u16* __restrict__ wt) {
  const int bid = blockIdx.x;
  const int tid = threadIdx.x;
  if (bid >= 4096) {  // ---- repack branch ----
    int i = (bid - 4096) * 256 + tid;
    if (i >= 110592) return;
    int j = i & 7, l = (i >> 3) & 63, kc = (i >> 9) & 3;
    int t2 = i >> 11;              // dydx*6 + ocg
    int ocg = t2 % 6, dydx = t2 / 6;
    int oc = ocg * 32 + (l & 31);
    int ch = kc * 16 + (l >> 5) * 8 + j;
    int cs = oc >> 6, ol = oc & 63;
    const float* src = cs == 0 ? wq : (cs == 1 ? wk : wv);
    wt[i] = f2bf(src[(ol * 64 + ch) * 9 + dydx]);
    return;
  }
  // ---- transpose branch ----
  __shared__ u16 t[64][130];
  const int wtile = bid & 1, h = (bid >> 1) & 255, n = bid >> 9;
  const int w0 = wtile << 7;
#pragma unroll
  for (int it = 0; it < 8; ++it) {
    int i = it * 256 + tid;
    int c = i >> 5, w4 = (i & 31) << 2;
    const f32x4 v = *(const f32x4*)(&x[(((long)((n << 6) + c)) << 16) + (h << 8) + w0 + w4]);
    unsigned p0 = (unsigned)f2bf(v[0]) | ((unsigned)f2bf(v[1]) << 16);
    unsigned p1 = (unsigned)f2bf(v[2]) | ((unsigned)f2bf(v[3]) << 16);
    *(unsigned*)(&t[c][w4]) = p0;
    *(unsigned*)(&t[c][w4 + 2]) = p1;
  }
  __syncthreads();
#pragma unroll
  for (int it = 0; it < 4; ++it) {
    int i = it * 256 + tid;
    int c8 = (i & 7) << 3, w = i >> 3;
    unsigned short u[8];
#pragma unroll
    for (int j = 0; j < 8; ++j) u[j] = t[c8 + j][w];
    uint4 val;
    val.x = (unsigned)u[0] | ((unsigned)u[1] << 16);
    val.y = (unsigned)u[2] | ((unsigned)u[3] << 16);
    val.z = (unsigned)u[4] | ((unsigned)u[5] << 16);
    val.w = (unsigned)u[6] | ((unsigned)u[7] << 16);
    *(uint4*)(xt + (long)((((n << 8) + h) << 8) + w0 + w) * 64 + c8) = val;
  }
}

// ---------------- K1: fused QKV conv3x3 as implicit GEMM (MFMA bf16) + channel stats ----------------
// R8 (unchanged in R9, control): 1 row x 128 w tile, mfma_f32_32x32x16_bf16, wave = 64px x 96oc.
// 160us, MfmaUtil 31.8, 4-way A-read conflict (8 XOR slots / 32 lanes) costs ~5us -- accepted.
__global__ __launch_bounds__(256, 2) void conv_k(const u16* __restrict__ xt,
                                                 const u16* __restrict__ wt,
                                                 u16* __restrict__ conv,
                                                 float* __restrict__ S) {
  __shared__ u16 lx[3 * 8320];  // 3 rows * 130 px * 64 ch = 49920 B
  const int bid = blockIdx.x;
  const int wtile = bid & 1, h = (bid >> 1) & 255, n = bid >> 9;
  const int w0 = wtile << 7;
  const int tid = threadIdx.x;
  for (int g = tid; g < 3120; g += 256) {
    int row = g / 1040;
    int r2 = g - row * 1040;
    int w = r2 >> 3, cg = r2 & 7;
    int hs = h + row - 1, wsr = w0 + w - 1;
    uint4 val = make_uint4(0u, 0u, 0u, 0u);
    if ((unsigned)hs < 256u && (unsigned)wsr < 256u)
      val = *(const uint4*)(xt + (long)((((n << 8) + hs) << 8) + wsr) * 64 + (cg << 3));
    int idx = ((w << 6) + (cg << 3)) ^ ((w & 7) << 3);
    *(uint4*)(&lx[row * 8320 + idx]) = val;
  }
  __syncthreads();
  const int lane = tid & 63, wave = tid >> 6;
  const int l31 = lane & 31, half = lane >> 5;
  const int wm = wave & 1, wn = wave >> 1;  // wm: px half (64), wn: oc group (96)
  f32x16 acc[3][2];
#pragma unroll
  for (int a = 0; a < 3; ++a)
#pragma unroll
    for (int b = 0; b < 2; ++b)
#pragma unroll
      for (int e = 0; e < 16; ++e) acc[a][b][e] = 0.f;

#pragma unroll
  for (int dy = 0; dy < 3; ++dy) {
#pragma unroll
    for (int dx = 0; dx < 3; ++dx) {
      const u16* wp = wt + (dy * 3 + dx) * 12288;
      short8 bfr[3][4];
#pragma unroll
      for (int nt = 0; nt < 3; ++nt)
#pragma unroll
        for (int kc = 0; kc < 4; ++kc)
          bfr[nt][kc] = *(const short8*)(wp + ((wn * 3 + nt) * 4 + kc) * 512 + lane * 8);
#pragma unroll
      for (int kc = 0; kc < 4; ++kc) {
        short8 afr[2];
#pragma unroll
        for (int mt = 0; mt < 2; ++mt) {
          const int px = wm * 64 + mt * 32 + l31 + dx;       // staged col (0..129)
          const int chb = kc * 16 + half * 8;                // k-slice base channel
          int idx = ((px << 6) + chb) ^ ((px & 7) << 3);
          afr[mt] = *(const short8*)(&lx[dy * 8320 + idx]);
        }
#pragma unroll
        for (int mt = 0; mt < 2; ++mt)
#pragma unroll
          for (int nt = 0; nt < 3; ++nt)
            acc[nt][mt] = __builtin_amdgcn_mfma_f32_32x32x16_bf16(afr[mt], bfr[nt][kc], acc[nt][mt], 0, 0, 0);
      }
    }
  }
  // epilogue: C col = l31 (oc), row = (r&3) + 8*(r>>2) + 4*half (px); store bf16 [pixel][192]
  const long pix0 = (long)bid * 128 + wm * 64;
#pragma unroll
  for (int nt = 0; nt < 3; ++nt) {
    const int oc = wn * 96 + nt * 32 + l31;
#pragma unroll
    for (int mt = 0; mt < 2; ++mt) {
      const long pxb = pix0 + mt * 32 + half * 4;
#pragma unroll
      for (int rq = 0; rq < 4; ++rq)
#pragma unroll
        for (int rr = 0; rr < 4; ++rr) {
          const long px = pxb + rr + 8 * rq;
          conv[px * 192 + oc] = f2bf(acc[nt][mt][rq * 4 + rr]);
        }
    }
  }
  // fused per-channel stats
  const int sh = (bid & 3) * 192;
#pragma unroll
  for (int nt = 0; nt < 3; ++nt) {
    float s = 0.f, ss = 0.f;
#pragma unroll
    for (int mt = 0; mt < 2; ++mt)
#pragma unroll
      for (int r = 0; r < 16; ++r) {
        float x = acc[nt][mt][r];
        s += x; ss += x * x;
      }
    s += __shfl_xor(s, 32); ss += __shfl_xor(ss, 32);
    if (lane < 32) {
      const int oc = wn * 96 + nt * 32 + lane;
      atomicAdd(&S[S_SUM + sh + oc], s);
      atomicAdd(&S[S_SSQ + sh + oc], ss);
    }
  }
}

// ---------------- K3: BN+sigmoid q,k,v; asp per pixel; 8 moments per (n,c) ----------------
// R9: BN params (former bnparam_k) recomputed per-block in LDS -- kills one launch; inputs
// are 26KB L2-hot S reads. DPP channel reduce (R6): 0 DS ops in the hot loop.
__global__ void k3_k(const u16* __restrict__ conv, float* __restrict__ S, float* __restrict__ asp,
                     const float* __restrict__ gq, const float* __restrict__ bq,
                     const float* __restrict__ gk, const float* __restrict__ bk,
                     const float* __restrict__ gv, const float* __restrict__ bv) {
  __shared__ float red[4][8][64];
  __shared__ float scb[192], bib[192];
  const int tid = threadIdx.x, lane = tid & 63, wave = tid >> 6;
  const int bid = blockIdx.x;          // 4096 blocks x 128 px
  const int n = bid >> 9;
  const long p0 = (long)bid * 128 + wave * 32;
  if (tid < 192) {
    int cv = tid >> 6, c = tid & 63;
    float g = cv == 0 ? gq[c] : (cv == 1 ? gk[c] : gv[c]);
    float b = cv == 0 ? bq[c] : (cv == 1 ? bk[c] : bv[c]);
    float sm = 0.f, sq2 = 0.f;
#pragma unroll
    for (int sh = 0; sh < 4; ++sh) { sm += S[S_SUM + sh * 192 + tid]; sq2 += S[S_SSQ + sh * 192 + tid]; }
    const float inv = 1.f / 524288.f;
    float mean = sm * inv;
    float var = sq2 * inv - mean * mean;
    float rstd = rsqrtf(var + 1e-5f);
    float sc = g * rstd;
    scb[tid] = sc;
    bib[tid] = b - mean * sc;
  }
  __syncthreads();
  const float sq = scb[lane], bq_ = bib[lane];
  const float sk = scb[64 + lane], bk_ = bib[64 + lane];
  const float sv = scb[128 + lane], bv_ = bib[128 + lane];
  float A1 = 0.f, A23 = 0.f, A45 = 0.f, V1 = 0.f, V2 = 0.f, AV = 0.f, AV2 = 0.f, A2V2 = 0.f;
  float myasp = 0.f;
#pragma unroll 4
  for (int i = 0; i < 32; ++i) {
    const u16* row = conv + (p0 + i) * 192;
    float q = sigmoidf_(bf2f(row[lane]) * sq + bq_);
    float k = sigmoidf_(bf2f(row[64 + lane]) * sk + bk_);
    float v = sigmoidf_(bf2f(row[128 + lane]) * sv + bv_);
    float p1 = q * k, p23 = q * q + k * k, p45 = q + k;
    A1 += p1; A23 += p23; A45 += p45;
    float s1 = wsum64(p1);
    float s23 = wsum64(p23);
    float s45 = wsum64(p45);
    const float sm = 1e-5f;
    float t1 = (s1 + sm) * frcp(s23 - s1 + sm);
    float t2 = (64.f - s45 + s1 + sm) * frcp(64.f - s45 + s23 - s1 + sm);
    float a = 0.5f * (t1 + t2);
    if (i == (lane & 31)) myasp = a;
    float av = a * v;
    V1 += v; V2 += v * v; AV += av; AV2 += av * v; A2V2 += av * av;
  }
  if (lane < 32) asp[p0 + lane] = myasp;
  red[wave][0][lane] = A1;  red[wave][1][lane] = A23; red[wave][2][lane] = A45;
  red[wave][3][lane] = V1;  red[wave][4][lane] = V2;  red[wave][5][lane] = AV;
  red[wave][6][lane] = AV2; red[wave][7][lane] = A2V2;
  __syncthreads();
  if (tid < 64) {
    const int mb[8] = {M_A1, M_A23, M_A45, M_V1, M_V2, M_AV, M_AV2, M_A2V2};
#pragma unroll
    for (int m = 0; m < 8; ++m) {
      float t = red[0][m][tid] + red[1][m][tid] + red[2][m][tid] + red[3][m][tid];
      atomicAdd(&S[mb[m] + n * 64 + tid], t);
    }
  }
}

// ---------------- K6: attention -> final BN -> NCHW fp32 out (LDS transpose) ----------------
// R9: former k4_k (attn_channel + final BN params) recomputed per-block from the 8 moment
// arrays (L2-hot, 64 threads x ~70 scalar reads) -- kills two launches (k4 + bnparam chain).
__global__ void k6_k(const u16* __restrict__ conv, const float* __restrict__ S,
                     const float* __restrict__ asp, float* __restrict__ out,
                     const float* __restrict__ gv, const float* __restrict__ bv,
                     const float* __restrict__ gn, const float* __restrict__ bn_) {
  __shared__ float t[128][65];
  __shared__ float svv[64], bvv[64], achb[64], sAv[64], bAv[64];
  const int tid = threadIdx.x, lane = tid & 63, wave = tid >> 6;
  const int n = blockIdx.x >> 9;
  const int hw0 = (blockIdx.x & 511) << 7;
  const long P0 = (long)blockIdx.x * 128;
  if (tid < 64) {
    const float inv = 1.f / 524288.f;
    // v BN params (c = tid)
    float sm = 0.f, sq2 = 0.f;
#pragma unroll
    for (int sh = 0; sh < 4; ++sh) {
      sm += S[S_SUM + sh * 192 + 128 + tid];
      sq2 += S[S_SSQ + sh * 192 + 128 + tid];
    }
    float mean = sm * inv;
    float var = sq2 * inv - mean * mean;
    float rstd = rsqrtf(var + 1e-5f);
    float sv = gv[tid] * rstd;
    svv[tid] = sv;
    bvv[tid] = bv[tid] - mean * sv;
    // attn_channel for own n + final BN params (reduce moments over all 8 n)
    const float smc = 1e-5f, cnt = 65536.f;
    float s1 = 0.f, s2 = 0.f, myach = 0.f;
#pragma unroll
    for (int nn = 0; nn < 8; ++nn) {
      int idx = nn * 64 + tid;
      float A1 = S[M_A1 + idx], A23 = S[M_A23 + idx], A45 = S[M_A45 + idx];
      float t1 = (A1 + smc) / (A23 - A1 + smc);
      float t2 = (cnt - A45 + A1 + smc) / (cnt - A45 + A23 - A1 + smc);
      float ach = 0.5f * (t1 + t2);
      if (nn == n) myach = ach;
      s1 += 0.5f * (S[M_AV + idx] + ach * S[M_V1 + idx]);
      s2 += 0.25f * (S[M_A2V2 + idx] + 2.f * ach * S[M_AV2 + idx] + ach * ach * S[M_V2 + idx]);
    }
    float mean2 = s1 * inv;
    float var2 = s2 * inv - mean2 * mean2;
    float rstd2 = rsqrtf(var2 + 1e-5f);
    float sA = gn[tid] * rstd2;
    sAv[tid] = sA;
    bAv[tid] = bn_[tid] - mean2 * sA;
    achb[tid] = myach;
  }
  __syncthreads();
  const float sv = svv[lane], bvx = bvv[lane];
  const float av = achb[lane];
  const float sA = sAv[lane], bA = bAv[lane];
  for (int i = wave; i < 128; i += 4) {
    const long p = P0 + i;
    float v = sigmoidf_(bf2f(conv[p * 192 + 128 + lane]) * sv + bvx);
    float att = 0.5f * (asp[p] + av) * v;
    t[i][lane] = att * sA + bA;
  }
  __syncthreads();
  const int c = tid >> 2, sub = tid & 3;
  const long plane = ((long)((n << 6) + c)) << 16;
  for (int i = 0; i < 8; ++i) {
    const int pst = (i * 4 + sub) << 2;
    f32x4 vbuf;
#pragma unroll
    for (int j = 0; j < 4; ++j) vbuf[j] = t[pst + j][c];
    *(f32x4*)(&out[plane + hw0 + pst]) = vbuf;
  }
}

extern "C" void kernel_launch(void* const* d_in, const int* in_sizes, int n_in,
                              void* d_out, int out_size, void* d_ws, size_t ws_size,
                              hipStream_t stream) {
  (void)in_sizes; (void)n_in; (void)out_size; (void)ws_size;
  const float* x  = (const float*)d_in[0];
  const float* wq = (const float*)d_in[1];
  const float* gq = (const float*)d_in[2];
  const float* bq = (const float*)d_in[3];
  const float* wk = (const float*)d_in[4];
  const float* gk = (const float*)d_in[5];
  const float* bk = (const float*)d_in[6];
  const float* wv = (const float*)d_in[7];
  const float* gv = (const float*)d_in[8];
  const float* bv = (const float*)d_in[9];
  const float* gn = (const float*)d_in[10];
  const float* bn_ = (const float*)d_in[11];
  char* ws = (char*)d_ws;
  float* S   = (float*)(ws + OFF_SUMS);
  u16* wt    = (u16*)(ws + OFF_WT);
  float* asp = (float*)(ws + OFF_ASP);
  u16* conv  = (u16*)(ws + OFF_CONV);
  float* out = (float*)d_out;
  u16* xt  = (u16*)d_out;  // bf16 NHWC scratch in first half of fp32 out; overwritten by k6_k

  (void)hipMemsetAsync(S, 0, S_NFLOAT * 4, stream);
  tr_k<<<4528, 256, 0, stream>>>(x, xt, wq, wk, wv, wt);
  conv_k<<<4096, 256, 0, stream>>>(xt, wt, conv, S);
  k3_k<<<4096, 256, 0, stream>>>(conv, S, asp, gq, bq, gk, bk, gv, bv);
  k6_k<<<4096, 256, 0, stream>>>(conv, S, asp, out, gv, bv, gn, bn_);
}

// Round 10
// 546.256 us; speedup vs baseline: 1.1820x; 1.0091x over previous
//
#include <hip/hip_runtime.h>

typedef unsigned short u16;
typedef __attribute__((ext_vector_type(8))) short short8;
typedef __attribute__((ext_vector_type(4))) float f32x4;
typedef __attribute__((ext_vector_type(16))) float f32x16;

// ---- ws layout (bytes) ----
#define OFF_SUMS 0ul              // 6656 floats = 26624
#define OFF_WT   26624ul          // 110592*2 = 221184 : weights bf16, fragment-major (see tr_k)
#define OFF_ASP  247808ul         // 524288*4 = 2097152 : attn_spatial fp32 [pixel]
#define OFF_CONV 2344960ul        // 524288*192*2 = 201326592 : raw conv out bf16 [pixel][192]
// xt (padded NHWC bf16 [8][258][258][64] = 68.2 MB, granule-swizzled) lives in d_out (134 MB);
// k6 overwrites it.
// ---- S (float) offsets ----
#define S_SUM   0      // conv channel sums, 4 shadows x 192
#define S_SSQ   768    // conv channel ssq, 4 shadows x 192
#define M_A1    1920   // per (n*64+c): sum q*k        [512]
#define M_A23   2432   // sum q^2+k^2                  [512]
#define M_A45   2944   // sum q+k                      [512]
#define M_V1    3456   // sum v                        [512]
#define M_V2    3968   // sum v^2                      [512]
#define M_AV    4480   // sum asp*v                    [512]
#define M_AV2   4992   // sum asp*v^2                  [512]
#define M_A2V2  5504   // sum asp^2*v^2                [512]
#define S_NFLOAT 6656

__device__ __forceinline__ float bf2f(u16 v) {
  union { unsigned u; float f; } x; x.u = ((unsigned)v) << 16; return x.f;
}
__device__ __forceinline__ u16 f2bf(float f) {
  union { float f; unsigned u; } x; x.f = f;
  unsigned r = x.u + 0x7fffu + ((x.u >> 16) & 1u);
  return (u16)(r >> 16);
}
// v_rcp_f32: ~1 ulp approx reciprocal; error 1e-7 rel, negligible vs bf16 data path (0.4%).
__device__ __forceinline__ float frcp(float x) { return __builtin_amdgcn_rcpf(x); }
__device__ __forceinline__ float sigmoidf_(float x) { return frcp(1.f + __expf(-x)); }

// ---- DPP wave64 sum (all-VALU, zero DS ops) ----
template <int CTRL, int RMASK>
__device__ __forceinline__ float dpp_add(float x) {
  int m = __builtin_amdgcn_update_dpp(0, __builtin_bit_cast(int, x), CTRL, RMASK, 0xf, true);
  return x + __builtin_bit_cast(float, m);
}
__device__ __forceinline__ float wsum64(float x) {
  x = dpp_add<0x111, 0xf>(x);  // row_shr:1
  x = dpp_add<0x112, 0xf>(x);  // row_shr:2
  x = dpp_add<0x114, 0xf>(x);  // row_shr:4
  x = dpp_add<0x118, 0xf>(x);  // row_shr:8
  x = dpp_add<0x142, 0xa>(x);  // row_bcast:15 -> rows 1,3
  x = dpp_add<0x143, 0xc>(x);  // row_bcast:31 -> rows 2,3
  return __builtin_bit_cast(float, __builtin_amdgcn_readlane(__builtin_bit_cast(int, x), 63));
}

// ---------------- K0: transpose (0..4095) + halo-zero (4096..4103) + repack (4104..) ----------
// R10: xt is PADDED [n][258][258][64] with a 1-px zero border, and each 128B pixel row is
// stored with its 16B granules XOR-swizzled by (padded_col & 7). conv_k then stages with
// global_load_lds (linear LDS dest) and still reads a swizzled layout (rule: linear dest +
// pre-swizzled source + swizzled read). w0 in {0,128} == 0 mod 8 keeps keys consistent.
__global__ void tr_k(const float* __restrict__ x, u16* __restrict__ xt,
                     const float* __restrict__ wq, const float* __restrict__ wk,
                     const float* __restrict__ wv, u16* __restrict__ wt) {
  const int bid = blockIdx.x;
  const int tid = threadIdx.x;
  if (bid >= 4104) {  // ---- repack branch ----
    int i = (bid - 4104) * 256 + tid;
    if (i >= 110592) return;
    int j = i & 7, l = (i >> 3) & 63, kc = (i >> 9) & 3;
    int t2 = i >> 11;              // dydx*6 + ocg
    int ocg = t2 % 6, dydx = t2 / 6;
    int oc = ocg * 32 + (l & 31);
    int ch = kc * 16 + (l >> 5) * 8 + j;
    int cs = oc >> 6, ol = oc & 63;
    const float* src = cs == 0 ? wq : (cs == 1 ? wk : wv);
    wt[i] = f2bf(src[(ol * 64 + ch) * 9 + dydx]);
    return;
  }
  if (bid >= 4096) {  // ---- halo-zero branch: 1-px border of padded image n ----
    const int n = bid - 4096;
    const uint4 z = make_uint4(0u, 0u, 0u, 0u);
    for (int t = tid; t < 8224; t += 256) {
      int cell = t >> 3, g = t & 7;
      int row, col;
      if (cell < 258) { row = 0; col = cell; }
      else if (cell < 516) { row = 257; col = cell - 258; }
      else if (cell < 772) { row = cell - 516 + 1; col = 0; }
      else { row = cell - 772 + 1; col = 257; }
      *(uint4*)(xt + ((long)(n * 258 + row) * 258 + col) * 64 + (g << 3)) = z;
    }
    return;
  }
  // ---- transpose branch (vectorized, R9) ----
  __shared__ u16 t[64][130];
  const int wtile = bid & 1, h = (bid >> 1) & 255, n = bid >> 9;
  const int w0 = wtile << 7;
#pragma unroll
  for (int it = 0; it < 8; ++it) {
    int i = it * 256 + tid;
    int c = i >> 5, w4 = (i & 31) << 2;
    const f32x4 v = *(const f32x4*)(&x[(((long)((n << 6) + c)) << 16) + (h << 8) + w0 + w4]);
    unsigned p0 = (unsigned)f2bf(v[0]) | ((unsigned)f2bf(v[1]) << 16);
    unsigned p1 = (unsigned)f2bf(v[2]) | ((unsigned)f2bf(v[3]) << 16);
    *(unsigned*)(&t[c][w4]) = p0;
    *(unsigned*)(&t[c][w4 + 2]) = p1;
  }
  __syncthreads();
#pragma unroll
  for (int it = 0; it < 4; ++it) {
    int i = it * 256 + tid;
    int g = i & 7, w = i >> 3;          // granule g = channels g*8..g*8+7, col w
    int c8 = g << 3;
    unsigned short u[8];
#pragma unroll
    for (int j = 0; j < 8; ++j) u[j] = t[c8 + j][w];
    uint4 val;
    val.x = (unsigned)u[0] | ((unsigned)u[1] << 16);
    val.y = (unsigned)u[2] | ((unsigned)u[3] << 16);
    val.z = (unsigned)u[4] | ((unsigned)u[5] << 16);
    val.w = (unsigned)u[6] | ((unsigned)u[7] << 16);
    const int pw = w0 + w + 1;          // padded col
    const int gs = g ^ (pw & 7);        // pre-swizzled granule
    *(uint4*)(xt + ((long)(n * 258 + h + 1) * 258 + pw) * 64 + (gs << 3)) = val;
  }
}

// ---------------- K1: fused QKV conv3x3 as implicit GEMM (MFMA bf16) + channel stats ----------------
// R10: staging via global_load_lds width=16 from padded pre-swizzled xt. 3 strips x 136 px x
// 128B = 17x1024B chunks each (51 total, wave-strided); no bounds checks (zero border), no
// VGPR round-trip, async under the barrier drain. Compute loop unchanged from R8.
__global__ __launch_bounds__(256, 2) void conv_k(const u16* __restrict__ xt,
                                                 const u16* __restrict__ wt,
                                                 u16* __restrict__ conv,
                                                 float* __restrict__ S) {
  __shared__ u16 lx[3 * 8704];  // 3 strips * 136 px * 64 ch = 52224 B (px 130..135 unused)
  const int bid = blockIdx.x;
  const int wtile = bid & 1, h = (bid >> 1) & 255, n = bid >> 9;
  const int w0 = wtile << 7;
  const int tid = threadIdx.x;
  const int lane = tid & 63, wave = tid >> 6;
  {
    // strip s: padded row h+s (= global rows h-1..h+1), padded cols w0.. (= global w0-1..)
    const long rowbase = ((long)(n * 258 + h) * 258 + w0) * 64;
    for (int c = wave; c < 51; c += 4) {
      const int s = (c >= 34) ? 2 : (c >= 17 ? 1 : 0);
      const int lc = c - s * 17;
      const int loff = s * 8704 + lc * 512 + lane * 8;
      const long goff = rowbase + (long)s * 16512 + lc * 512 + lane * 8;  // 258*64=16512
      __builtin_amdgcn_global_load_lds(
          (const __attribute__((address_space(1))) unsigned int*)(xt + goff),
          (__attribute__((address_space(3))) unsigned int*)(&lx[loff]), 16, 0, 0);
    }
  }
  __syncthreads();
  const int l31 = lane & 31, half = lane >> 5;
  const int wm = wave & 1, wn = wave >> 1;  // wm: px half (64), wn: oc group (96)
  f32x16 acc[3][2];
#pragma unroll
  for (int a = 0; a < 3; ++a)
#pragma unroll
    for (int b = 0; b < 2; ++b)
#pragma unroll
      for (int e = 0; e < 16; ++e) acc[a][b][e] = 0.f;

#pragma unroll
  for (int dy = 0; dy < 3; ++dy) {
#pragma unroll
    for (int dx = 0; dx < 3; ++dx) {
      const u16* wp = wt + (dy * 3 + dx) * 12288;
      short8 bfr[3][4];
#pragma unroll
      for (int nt = 0; nt < 3; ++nt)
#pragma unroll
        for (int kc = 0; kc < 4; ++kc)
          bfr[nt][kc] = *(const short8*)(wp + ((wn * 3 + nt) * 4 + kc) * 512 + lane * 8);
#pragma unroll
      for (int kc = 0; kc < 4; ++kc) {
        short8 afr[2];
#pragma unroll
        for (int mt = 0; mt < 2; ++mt) {
          const int px = wm * 64 + mt * 32 + l31 + dx;       // staged col (0..129)
          const int chb = kc * 16 + half * 8;                // k-slice base channel
          int idx = ((px << 6) + chb) ^ ((px & 7) << 3);
          afr[mt] = *(const short8*)(&lx[dy * 8704 + idx]);
        }
#pragma unroll
        for (int mt = 0; mt < 2; ++mt)
#pragma unroll
          for (int nt = 0; nt < 3; ++nt)
            acc[nt][mt] = __builtin_amdgcn_mfma_f32_32x32x16_bf16(afr[mt], bfr[nt][kc], acc[nt][mt], 0, 0, 0);
      }
    }
  }
  // epilogue: C col = l31 (oc), row = (r&3) + 8*(r>>2) + 4*half (px); store bf16 [pixel][192]
  const long pix0 = (long)bid * 128 + wm * 64;
#pragma unroll
  for (int nt = 0; nt < 3; ++nt) {
    const int oc = wn * 96 + nt * 32 + l31;
#pragma unroll
    for (int mt = 0; mt < 2; ++mt) {
      const long pxb = pix0 + mt * 32 + half * 4;
#pragma unroll
      for (int rq = 0; rq < 4; ++rq)
#pragma unroll
        for (int rr = 0; rr < 4; ++rr) {
          const long px = pxb + rr + 8 * rq;
          conv[px * 192 + oc] = f2bf(acc[nt][mt][rq * 4 + rr]);
        }
    }
  }
  // fused per-channel stats
  const int sh = (bid & 3) * 192;
#pragma unroll
  for (int nt = 0; nt < 3; ++nt) {
    float s = 0.f, ss = 0.f;
#pragma unroll
    for (int mt = 0; mt < 2; ++mt)
#pragma unroll
      for (int r = 0; r < 16; ++r) {
        float x = acc[nt][mt][r];
        s += x; ss += x * x;
      }
    s += __shfl_xor(s, 32); ss += __shfl_xor(ss, 32);
    if (lane < 32) {
      const int oc = wn * 96 + nt * 32 + lane;
      atomicAdd(&S[S_SUM + sh + oc], s);
      atomicAdd(&S[S_SSQ + sh + oc], ss);
    }
  }
}

// ---------------- K3: BN+sigmoid q,k,v; asp per pixel; 8 moments per (n,c) ----------------
// BN params recomputed per-block in LDS (R9); DPP channel reduce (R6): 0 DS ops in hot loop.
__global__ void k3_k(const u16* __restrict__ conv, float* __restrict__ S, float* __restrict__ asp,
                     const float* __restrict__ gq, const float* __restrict__ bq,
                     const float* __restrict__ gk, const float* __restrict__ bk,
                     const float* __restrict__ gv, const float* __restrict__ bv) {
  __shared__ float red[4][8][64];
  __shared__ float scb[192], bib[192];
  const int tid = threadIdx.x, lane = tid & 63, wave = tid >> 6;
  const int bid = blockIdx.x;          // 4096 blocks x 128 px
  const int n = bid >> 9;
  const long p0 = (long)bid * 128 + wave * 32;
  if (tid < 192) {
    int cv = tid >> 6, c = tid & 63;
    float g = cv == 0 ? gq[c] : (cv == 1 ? gk[c] : gv[c]);
    float b = cv == 0 ? bq[c] : (cv == 1 ? bk[c] : bv[c]);
    float sm = 0.f, sq2 = 0.f;
#pragma unroll
    for (int sh = 0; sh < 4; ++sh) { sm += S[S_SUM + sh * 192 + tid]; sq2 += S[S_SSQ + sh * 192 + tid]; }
    const float inv = 1.f / 524288.f;
    float mean = sm * inv;
    float var = sq2 * inv - mean * mean;
    float rstd = rsqrtf(var + 1e-5f);
    float sc = g * rstd;
    scb[tid] = sc;
    bib[tid] = b - mean * sc;
  }
  __syncthreads();
  const float sq = scb[lane], bq_ = bib[lane];
  const float sk = scb[64 + lane], bk_ = bib[64 + lane];
  const float sv = scb[128 + lane], bv_ = bib[128 + lane];
  float A1 = 0.f, A23 = 0.f, A45 = 0.f, V1 = 0.f, V2 = 0.f, AV = 0.f, AV2 = 0.f, A2V2 = 0.f;
  float myasp = 0.f;
#pragma unroll 4
  for (int i = 0; i < 32; ++i) {
    const u16* row = conv + (p0 + i) * 192;
    float q = sigmoidf_(bf2f(row[lane]) * sq + bq_);
    float k = sigmoidf_(bf2f(row[64 + lane]) * sk + bk_);
    float v = sigmoidf_(bf2f(row[128 + lane]) * sv + bv_);
    float p1 = q * k, p23 = q * q + k * k, p45 = q + k;
    A1 += p1; A23 += p23; A45 += p45;
    float s1 = wsum64(p1);
    float s23 = wsum64(p23);
    float s45 = wsum64(p45);
    const float sm = 1e-5f;
    float t1 = (s1 + sm) * frcp(s23 - s1 + sm);
    float t2 = (64.f - s45 + s1 + sm) * frcp(64.f - s45 + s23 - s1 + sm);
    float a = 0.5f * (t1 + t2);
    if (i == (lane & 31)) myasp = a;
    float av = a * v;
    V1 += v; V2 += v * v; AV += av; AV2 += av * v; A2V2 += av * av;
  }
  if (lane < 32) asp[p0 + lane] = myasp;
  red[wave][0][lane] = A1;  red[wave][1][lane] = A23; red[wave][2][lane] = A45;
  red[wave][3][lane] = V1;  red[wave][4][lane] = V2;  red[wave][5][lane] = AV;
  red[wave][6][lane] = AV2; red[wave][7][lane] = A2V2;
  __syncthreads();
  if (tid < 64) {
    const int mb[8] = {M_A1, M_A23, M_A45, M_V1, M_V2, M_AV, M_AV2, M_A2V2};
#pragma unroll
    for (int m = 0; m < 8; ++m) {
      float t = red[0][m][tid] + red[1][m][tid] + red[2][m][tid] + red[3][m][tid];
      atomicAdd(&S[mb[m] + n * 64 + tid], t);
    }
  }
}

// ---------------- K6: attention -> final BN -> NCHW fp32 out (LDS transpose) ----------------
// attn_channel + final BN params recomputed per-block from L2-hot moment arrays (R9).
__global__ void k6_k(const u16* __restrict__ conv, const float* __restrict__ S,
                     const float* __restrict__ asp, float* __restrict__ out,
                     const float* __restrict__ gv, const float* __restrict__ bv,
                     const float* __restrict__ gn, const float* __restrict__ bn_) {
  __shared__ float t[128][65];
  __shared__ float svv[64], bvv[64], achb[64], sAv[64], bAv[64];
  const int tid = threadIdx.x, lane = tid & 63, wave = tid >> 6;
  const int n = blockIdx.x >> 9;
  const int hw0 = (blockIdx.x & 511) << 7;
  const long P0 = (long)blockIdx.x * 128;
  if (tid < 64) {
    const float inv = 1.f / 524288.f;
    float sm = 0.f, sq2 = 0.f;
#pragma unroll
    for (int sh = 0; sh < 4; ++sh) {
      sm += S[S_SUM + sh * 192 + 128 + tid];
      sq2 += S[S_SSQ + sh * 192 + 128 + tid];
    }
    float mean = sm * inv;
    float var = sq2 * inv - mean * mean;
    float rstd = rsqrtf(var + 1e-5f);
    float sv = gv[tid] * rstd;
    svv[tid] = sv;
    bvv[tid] = bv[tid] - mean * sv;
    const float smc = 1e-5f, cnt = 65536.f;
    float s1 = 0.f, s2 = 0.f, myach = 0.f;
#pragma unroll
    for (int nn = 0; nn < 8; ++nn) {
      int idx = nn * 64 + tid;
      float A1 = S[M_A1 + idx], A23 = S[M_A23 + idx], A45 = S[M_A45 + idx];
      float t1 = (A1 + smc) / (A23 - A1 + smc);
      float t2 = (cnt - A45 + A1 + smc) / (cnt - A45 + A23 - A1 + smc);
      float ach = 0.5f * (t1 + t2);
      if (nn == n) myach = ach;
      s1 += 0.5f * (S[M_AV + idx] + ach * S[M_V1 + idx]);
      s2 += 0.25f * (S[M_A2V2 + idx] + 2.f * ach * S[M_AV2 + idx] + ach * ach * S[M_V2 + idx]);
    }
    float mean2 = s1 * inv;
    float var2 = s2 * inv - mean2 * mean2;
    float rstd2 = rsqrtf(var2 + 1e-5f);
    float sA = gn[tid] * rstd2;
    sAv[tid] = sA;
    bAv[tid] = bn_[tid] - mean2 * sA;
    achb[tid] = myach;
  }
  __syncthreads();
  const float sv = svv[lane], bvx = bvv[lane];
  const float av = achb[lane];
  const float sA = sAv[lane], bA = bAv[lane];
  for (int i = wave; i < 128; i += 4) {
    const long p = P0 + i;
    float v = sigmoidf_(bf2f(conv[p * 192 + 128 + lane]) * sv + bvx);
    float att = 0.5f * (asp[p] + av) * v;
    t[i][lane] = att * sA + bA;
  }
  __syncthreads();
  const int c = tid >> 2, sub = tid & 3;
  const long plane = ((long)((n << 6) + c)) << 16;
  for (int i = 0; i < 8; ++i) {
    const int pst = (i * 4 + sub) << 2;
    f32x4 vbuf;
#pragma unroll
    for (int j = 0; j < 4; ++j) vbuf[j] = t[pst + j][c];
    *(f32x4*)(&out[plane + hw0 + pst]) = vbuf;
  }
}

extern "C" void kernel_launch(void* const* d_in, const int* in_sizes, int n_in,
                              void* d_out, int out_size, void* d_ws, size_t ws_size,
                              hipStream_t stream) {
  (void)in_sizes; (void)n_in; (void)out_size; (void)ws_size;
  const float* x  = (const float*)d_in[0];
  const float* wq = (const float*)d_in[1];
  const float* gq = (const float*)d_in[2];
  const float* bq = (const float*)d_in[3];
  const float* wk = (const float*)d_in[4];
  const float* gk = (const float*)d_in[5];
  const float* bk = (const float*)d_in[6];
  const float* wv = (const float*)d_in[7];
  const float* gv = (const float*)d_in[8];
  const float* bv = (const float*)d_in[9];
  const float* gn = (const float*)d_in[10];
  const float* bn_ = (const float*)d_in[11];
  char* ws = (char*)d_ws;
  float* S   = (float*)(ws + OFF_SUMS);
  u16* wt    = (u16*)(ws + OFF_WT);
  float* asp = (float*)(ws + OFF_ASP);
  u16* conv  = (u16*)(ws + OFF_CONV);
  float* out = (float*)d_out;
  u16* xt  = (u16*)d_out;  // padded pre-swizzled bf16 scratch in d_out; overwritten by k6_k

  (void)hipMemsetAsync(S, 0, S_NFLOAT * 4, stream);
  tr_k<<<4536, 256, 0, stream>>>(x, xt, wq, wk, wv, wt);
  conv_k<<<4096, 256, 0, stream>>>(xt, wt, conv, S);
  k3_k<<<4096, 256, 0, stream>>>(conv, S, asp, gq, bq, gk, bk, gv, bv);
  k6_k<<<4096, 256, 0, stream>>>(conv, S, asp, out, gv, bv, gn, bn_);
}

// Round 11
// 537.063 us; speedup vs baseline: 1.2023x; 1.0171x over previous
//
#include <hip/hip_runtime.h>

typedef unsigned short u16;
typedef __attribute__((ext_vector_type(8))) short short8;
typedef __attribute__((ext_vector_type(4))) float f32x4;
typedef __attribute__((ext_vector_type(16))) float f32x16;

// ---- ws layout (bytes) ----
#define OFF_SUMS 0ul              // 6656 floats = 26624
#define OFF_WT   26624ul          // 110592*2 = 221184 : weights bf16, fragment-major (see tr_k)
#define OFF_ASP  247808ul         // 524288*4 = 2097152 : attn_spatial fp32 [pixel]
#define OFF_CONV 2344960ul        // 524288*192*2 = 201326592 : raw conv out bf16 [pixel][192]
// xt (padded NHWC bf16 [8][258][258][64] = 68.2 MB, granule-swizzled) lives in d_out (134 MB);
// k6 overwrites it.
// ---- S (float) offsets ----
#define S_SUM   0      // conv channel sums, 4 shadows x 192
#define S_SSQ   768    // conv channel ssq, 4 shadows x 192
#define M_A1    1920   // per (n*64+c): sum q*k        [512]
#define M_A23   2432   // sum q^2+k^2                  [512]
#define M_A45   2944   // sum q+k                      [512]
#define M_V1    3456   // sum v                        [512]
#define M_V2    3968   // sum v^2                      [512]
#define M_AV    4480   // sum asp*v                    [512]
#define M_AV2   4992   // sum asp*v^2                  [512]
#define M_A2V2  5504   // sum asp^2*v^2                [512]
#define S_NFLOAT 6656

__device__ __forceinline__ float bf2f(u16 v) {
  union { unsigned u; float f; } x; x.u = ((unsigned)v) << 16; return x.f;
}
__device__ __forceinline__ u16 f2bf(float f) {
  union { float f; unsigned u; } x; x.f = f;
  unsigned r = x.u + 0x7fffu + ((x.u >> 16) & 1u);
  return (u16)(r >> 16);
}
// v_rcp_f32: ~1 ulp approx reciprocal; error 1e-7 rel, negligible vs bf16 data path (0.4%).
__device__ __forceinline__ float frcp(float x) { return __builtin_amdgcn_rcpf(x); }
__device__ __forceinline__ float sigmoidf_(float x) { return frcp(1.f + __expf(-x)); }

// ---- DPP wave64 sum (all-VALU, zero DS ops) ----
template <int CTRL, int RMASK>
__device__ __forceinline__ float dpp_add(float x) {
  int m = __builtin_amdgcn_update_dpp(0, __builtin_bit_cast(int, x), CTRL, RMASK, 0xf, true);
  return x + __builtin_bit_cast(float, m);
}
__device__ __forceinline__ float wsum64(float x) {
  x = dpp_add<0x111, 0xf>(x);  // row_shr:1
  x = dpp_add<0x112, 0xf>(x);  // row_shr:2
  x = dpp_add<0x114, 0xf>(x);  // row_shr:4
  x = dpp_add<0x118, 0xf>(x);  // row_shr:8
  x = dpp_add<0x142, 0xa>(x);  // row_bcast:15 -> rows 1,3
  x = dpp_add<0x143, 0xc>(x);  // row_bcast:31 -> rows 2,3
  return __builtin_bit_cast(float, __builtin_amdgcn_readlane(__builtin_bit_cast(int, x), 63));
}

// ---------------- K0: transpose (0..4095) + halo-zero (4096..4103) + repack (4104..4535)
//                   + S-zero (4536) ----------
// xt is PADDED [n][258][258][64] with a 1-px zero border; each 128B pixel row is stored with
// its 16B granules XOR-swizzled by (padded_col & 7). conv_k stages with global_load_lds
// (linear LDS dest + pre-swizzled source + swizzled read). R11: S-zero folded in (block 4536)
// -- tr_k completes before conv_k launches, so ordering == old hipMemsetAsync.
__global__ void tr_k(const float* __restrict__ x, u16* __restrict__ xt,
                     const float* __restrict__ wq, const float* __restrict__ wk,
                     const float* __restrict__ wv, u16* __restrict__ wt,
                     float* __restrict__ S) {
  const int bid = blockIdx.x;
  const int tid = threadIdx.x;
  if (bid == 4536) {  // ---- S-zero branch ----
    for (int i = tid; i < S_NFLOAT; i += 256) S[i] = 0.f;
    return;
  }
  if (bid >= 4104) {  // ---- repack branch ----
    int i = (bid - 4104) * 256 + tid;
    if (i >= 110592) return;
    int j = i & 7, l = (i >> 3) & 63, kc = (i >> 9) & 3;
    int t2 = i >> 11;              // dydx*6 + ocg
    int ocg = t2 % 6, dydx = t2 / 6;
    int oc = ocg * 32 + (l & 31);
    int ch = kc * 16 + (l >> 5) * 8 + j;
    int cs = oc >> 6, ol = oc & 63;
    const float* src = cs == 0 ? wq : (cs == 1 ? wk : wv);
    wt[i] = f2bf(src[(ol * 64 + ch) * 9 + dydx]);
    return;
  }
  if (bid >= 4096) {  // ---- halo-zero branch: 1-px border of padded image n ----
    const int n = bid - 4096;
    const uint4 z = make_uint4(0u, 0u, 0u, 0u);
    for (int t = tid; t < 8224; t += 256) {
      int cell = t >> 3, g = t & 7;
      int row, col;
      if (cell < 258) { row = 0; col = cell; }
      else if (cell < 516) { row = 257; col = cell - 258; }
      else if (cell < 772) { row = cell - 516 + 1; col = 0; }
      else { row = cell - 772 + 1; col = 257; }
      *(uint4*)(xt + ((long)(n * 258 + row) * 258 + col) * 64 + (g << 3)) = z;
    }
    return;
  }
  // ---- transpose branch (vectorized, R9) ----
  __shared__ u16 t[64][130];
  const int wtile = bid & 1, h = (bid >> 1) & 255, n = bid >> 9;
  const int w0 = wtile << 7;
#pragma unroll
  for (int it = 0; it < 8; ++it) {
    int i = it * 256 + tid;
    int c = i >> 5, w4 = (i & 31) << 2;
    const f32x4 v = *(const f32x4*)(&x[(((long)((n << 6) + c)) << 16) + (h << 8) + w0 + w4]);
    unsigned p0 = (unsigned)f2bf(v[0]) | ((unsigned)f2bf(v[1]) << 16);
    unsigned p1 = (unsigned)f2bf(v[2]) | ((unsigned)f2bf(v[3]) << 16);
    *(unsigned*)(&t[c][w4]) = p0;
    *(unsigned*)(&t[c][w4 + 2]) = p1;
  }
  __syncthreads();
#pragma unroll
  for (int it = 0; it < 4; ++it) {
    int i = it * 256 + tid;
    int g = i & 7, w = i >> 3;          // granule g = channels g*8..g*8+7, col w
    int c8 = g << 3;
    unsigned short u[8];
#pragma unroll
    for (int j = 0; j < 8; ++j) u[j] = t[c8 + j][w];
    uint4 val;
    val.x = (unsigned)u[0] | ((unsigned)u[1] << 16);
    val.y = (unsigned)u[2] | ((unsigned)u[3] << 16);
    val.z = (unsigned)u[4] | ((unsigned)u[5] << 16);
    val.w = (unsigned)u[6] | ((unsigned)u[7] << 16);
    const int pw = w0 + w + 1;          // padded col
    const int gs = g ^ (pw & 7);        // pre-swizzled granule
    *(uint4*)(xt + ((long)(n * 258 + h + 1) * 258 + pw) * 64 + (gs << 3)) = val;
  }
}

// ---------------- K1: fused QKV conv3x3 as implicit GEMM (MFMA bf16) + channel stats ----------------
// R10 staging (global_load_lds width=16 from padded pre-swizzled xt) + R11: tap-(0,0)
// B-fragment loads hoisted ABOVE __syncthreads -- they have no LDS dependence, so they
// overlap the staging drain instead of serializing after the barrier.
__global__ __launch_bounds__(256, 2) void conv_k(const u16* __restrict__ xt,
                                                 const u16* __restrict__ wt,
                                                 u16* __restrict__ conv,
                                                 float* __restrict__ S) {
  __shared__ u16 lx[3 * 8704];  // 3 strips * 136 px * 64 ch = 52224 B (px 130..135 unused)
  const int bid = blockIdx.x;
  const int wtile = bid & 1, h = (bid >> 1) & 255, n = bid >> 9;
  const int w0 = wtile << 7;
  const int tid = threadIdx.x;
  const int lane = tid & 63, wave = tid >> 6;
  const int l31 = lane & 31, half = lane >> 5;
  const int wm = wave & 1, wn = wave >> 1;  // wm: px half (64), wn: oc group (96)
  {
    // strip s: padded row h+s (= global rows h-1..h+1), padded cols w0.. (= global w0-1..)
    const long rowbase = ((long)(n * 258 + h) * 258 + w0) * 64;
    for (int c = wave; c < 51; c += 4) {
      const int s = (c >= 34) ? 2 : (c >= 17 ? 1 : 0);
      const int lc = c - s * 17;
      const int loff = s * 8704 + lc * 512 + lane * 8;
      const long goff = rowbase + (long)s * 16512 + lc * 512 + lane * 8;  // 258*64=16512
      __builtin_amdgcn_global_load_lds(
          (const __attribute__((address_space(1))) unsigned int*)(xt + goff),
          (__attribute__((address_space(3))) unsigned int*)(&lx[loff]), 16, 0, 0);
    }
  }
  // R11: prefetch tap-(0,0) B fragments before the barrier (independent of LDS staging)
  short8 bfr0[3][4];
#pragma unroll
  for (int nt = 0; nt < 3; ++nt)
#pragma unroll
    for (int kc = 0; kc < 4; ++kc)
      bfr0[nt][kc] = *(const short8*)(wt + ((wn * 3 + nt) * 4 + kc) * 512 + lane * 8);
  __syncthreads();
  f32x16 acc[3][2];
#pragma unroll
  for (int a = 0; a < 3; ++a)
#pragma unroll
    for (int b = 0; b < 2; ++b)
#pragma unroll
      for (int e = 0; e < 16; ++e) acc[a][b][e] = 0.f;

#pragma unroll
  for (int dy = 0; dy < 3; ++dy) {
#pragma unroll
    for (int dx = 0; dx < 3; ++dx) {
      const u16* wp = wt + (dy * 3 + dx) * 12288;
      short8 bfr[3][4];
#pragma unroll
      for (int nt = 0; nt < 3; ++nt)
#pragma unroll
        for (int kc = 0; kc < 4; ++kc)
          bfr[nt][kc] = (dy == 0 && dx == 0) ? bfr0[nt][kc]
                        : *(const short8*)(wp + ((wn * 3 + nt) * 4 + kc) * 512 + lane * 8);
#pragma unroll
      for (int kc = 0; kc < 4; ++kc) {
        short8 afr[2];
#pragma unroll
        for (int mt = 0; mt < 2; ++mt) {
          const int px = wm * 64 + mt * 32 + l31 + dx;       // staged col (0..129)
          const int chb = kc * 16 + half * 8;                // k-slice base channel
          int idx = ((px << 6) + chb) ^ ((px & 7) << 3);
          afr[mt] = *(const short8*)(&lx[dy * 8704 + idx]);
        }
#pragma unroll
        for (int mt = 0; mt < 2; ++mt)
#pragma unroll
          for (int nt = 0; nt < 3; ++nt)
            acc[nt][mt] = __builtin_amdgcn_mfma_f32_32x32x16_bf16(afr[mt], bfr[nt][kc], acc[nt][mt], 0, 0, 0);
      }
    }
  }
  // epilogue: C col = l31 (oc), row = (r&3) + 8*(r>>2) + 4*half (px); store bf16 [pixel][192]
  const long pix0 = (long)bid * 128 + wm * 64;
#pragma unroll
  for (int nt = 0; nt < 3; ++nt) {
    const int oc = wn * 96 + nt * 32 + l31;
#pragma unroll
    for (int mt = 0; mt < 2; ++mt) {
      const long pxb = pix0 + mt * 32 + half * 4;
#pragma unroll
      for (int rq = 0; rq < 4; ++rq)
#pragma unroll
        for (int rr = 0; rr < 4; ++rr) {
          const long px = pxb + rr + 8 * rq;
          conv[px * 192 + oc] = f2bf(acc[nt][mt][rq * 4 + rr]);
        }
    }
  }
  // fused per-channel stats
  const int sh = (bid & 3) * 192;
#pragma unroll
  for (int nt = 0; nt < 3; ++nt) {
    float s = 0.f, ss = 0.f;
#pragma unroll
    for (int mt = 0; mt < 2; ++mt)
#pragma unroll
      for (int r = 0; r < 16; ++r) {
        float x = acc[nt][mt][r];
        s += x; ss += x * x;
      }
    s += __shfl_xor(s, 32); ss += __shfl_xor(ss, 32);
    if (lane < 32) {
      const int oc = wn * 96 + nt * 32 + lane;
      atomicAdd(&S[S_SUM + sh + oc], s);
      atomicAdd(&S[S_SSQ + sh + oc], ss);
    }
  }
}

// ---------------- K3: BN+sigmoid q,k,v; asp per pixel; 8 moments per (n,c) ----------------
// BN params recomputed per-block in LDS (R9); DPP channel reduce (R6): 0 DS ops in hot loop.
__global__ void k3_k(const u16* __restrict__ conv, float* __restrict__ S, float* __restrict__ asp,
                     const float* __restrict__ gq, const float* __restrict__ bq,
                     const float* __restrict__ gk, const float* __restrict__ bk,
                     const float* __restrict__ gv, const float* __restrict__ bv) {
  __shared__ float red[4][8][64];
  __shared__ float scb[192], bib[192];
  const int tid = threadIdx.x, lane = tid & 63, wave = tid >> 6;
  const int bid = blockIdx.x;          // 4096 blocks x 128 px
  const int n = bid >> 9;
  const long p0 = (long)bid * 128 + wave * 32;
  if (tid < 192) {
    int cv = tid >> 6, c = tid & 63;
    float g = cv == 0 ? gq[c] : (cv == 1 ? gk[c] : gv[c]);
    float b = cv == 0 ? bq[c] : (cv == 1 ? bk[c] : bv[c]);
    float sm = 0.f, sq2 = 0.f;
#pragma unroll
    for (int sh = 0; sh < 4; ++sh) { sm += S[S_SUM + sh * 192 + tid]; sq2 += S[S_SSQ + sh * 192 + tid]; }
    const float inv = 1.f / 524288.f;
    float mean = sm * inv;
    float var = sq2 * inv - mean * mean;
    float rstd = rsqrtf(var + 1e-5f);
    float sc = g * rstd;
    scb[tid] = sc;
    bib[tid] = b - mean * sc;
  }
  __syncthreads();
  const float sq = scb[lane], bq_ = bib[lane];
  const float sk = scb[64 + lane], bk_ = bib[64 + lane];
  const float sv = scb[128 + lane], bv_ = bib[128 + lane];
  float A1 = 0.f, A23 = 0.f, A45 = 0.f, V1 = 0.f, V2 = 0.f, AV = 0.f, AV2 = 0.f, A2V2 = 0.f;
  float myasp = 0.f;
#pragma unroll 4
  for (int i = 0; i < 32; ++i) {
    const u16* row = conv + (p0 + i) * 192;
    float q = sigmoidf_(bf2f(row[lane]) * sq + bq_);
    float k = sigmoidf_(bf2f(row[64 + lane]) * sk + bk_);
    float v = sigmoidf_(bf2f(row[128 + lane]) * sv + bv_);
    float p1 = q * k, p23 = q * q + k * k, p45 = q + k;
    A1 += p1; A23 += p23; A45 += p45;
    float s1 = wsum64(p1);
    float s23 = wsum64(p23);
    float s45 = wsum64(p45);
    const float sm = 1e-5f;
    float t1 = (s1 + sm) * frcp(s23 - s1 + sm);
    float t2 = (64.f - s45 + s1 + sm) * frcp(64.f - s45 + s23 - s1 + sm);
    float a = 0.5f * (t1 + t2);
    if (i == (lane & 31)) myasp = a;
    float av = a * v;
    V1 += v; V2 += v * v; AV += av; AV2 += av * v; A2V2 += av * av;
  }
  if (lane < 32) asp[p0 + lane] = myasp;
  red[wave][0][lane] = A1;  red[wave][1][lane] = A23; red[wave][2][lane] = A45;
  red[wave][3][lane] = V1;  red[wave][4][lane] = V2;  red[wave][5][lane] = AV;
  red[wave][6][lane] = AV2; red[wave][7][lane] = A2V2;
  __syncthreads();
  if (tid < 64) {
    const int mb[8] = {M_A1, M_A23, M_A45, M_V1, M_V2, M_AV, M_AV2, M_A2V2};
#pragma unroll
    for (int m = 0; m < 8; ++m) {
      float t = red[0][m][tid] + red[1][m][tid] + red[2][m][tid] + red[3][m][tid];
      atomicAdd(&S[mb[m] + n * 64 + tid], t);
    }
  }
}

// ---------------- K6: attention -> final BN -> NCHW fp32 out (LDS transpose) ----------------
// attn_channel + final BN params recomputed per-block from L2-hot moment arrays (R9).
// R11: output stores re-mapped to 128B runs per channel (c=tid>>3, 8 subs x 16B, 2 c-loops)
// -- was 64B partial-line segments on the 134 MB fp32 output.
__global__ void k6_k(const u16* __restrict__ conv, const float* __restrict__ S,
                     const float* __restrict__ asp, float* __restrict__ out,
                     const float* __restrict__ gv, const float* __restrict__ bv,
                     const float* __restrict__ gn, const float* __restrict__ bn_) {
  __shared__ float t[128][65];
  __shared__ float svv[64], bvv[64], achb[64], sAv[64], bAv[64];
  const int tid = threadIdx.x, lane = tid & 63, wave = tid >> 6;
  const int n = blockIdx.x >> 9;
  const int hw0 = (blockIdx.x & 511) << 7;
  const long P0 = (long)blockIdx.x * 128;
  if (tid < 64) {
    const float inv = 1.f / 524288.f;
    float sm = 0.f, sq2 = 0.f;
#pragma unroll
    for (int sh = 0; sh < 4; ++sh) {
      sm += S[S_SUM + sh * 192 + 128 + tid];
      sq2 += S[S_SSQ + sh * 192 + 128 + tid];
    }
    float mean = sm * inv;
    float var = sq2 * inv - mean * mean;
    float rstd = rsqrtf(var + 1e-5f);
    float sv = gv[tid] * rstd;
    svv[tid] = sv;
    bvv[tid] = bv[tid] - mean * sv;
    const float smc = 1e-5f, cnt = 65536.f;
    float s1 = 0.f, s2 = 0.f, myach = 0.f;
#pragma unroll
    for (int nn = 0; nn < 8; ++nn) {
      int idx = nn * 64 + tid;
      float A1 = S[M_A1 + idx], A23 = S[M_A23 + idx], A45 = S[M_A45 + idx];
      float t1 = (A1 + smc) / (A23 - A1 + smc);
      float t2 = (cnt - A45 + A1 + smc) / (cnt - A45 + A23 - A1 + smc);
      float ach = 0.5f * (t1 + t2);
      if (nn == n) myach = ach;
      s1 += 0.5f * (S[M_AV + idx] + ach * S[M_V1 + idx]);
      s2 += 0.25f * (S[M_A2V2 + idx] + 2.f * ach * S[M_AV2 + idx] + ach * ach * S[M_V2 + idx]);
    }
    float mean2 = s1 * inv;
    float var2 = s2 * inv - mean2 * mean2;
    float rstd2 = rsqrtf(var2 + 1e-5f);
    float sA = gn[tid] * rstd2;
    sAv[tid] = sA;
    bAv[tid] = bn_[tid] - mean2 * sA;
    achb[tid] = myach;
  }
  __syncthreads();
  const float sv = svv[lane], bvx = bvv[lane];
  const float av = achb[lane];
  const float sA = sAv[lane], bA = bAv[lane];
  for (int i = wave; i < 128; i += 4) {
    const long p = P0 + i;
    float v = sigmoidf_(bf2f(conv[p * 192 + 128 + lane]) * sv + bvx);
    float att = 0.5f * (asp[p] + av) * v;
    t[i][lane] = att * sA + bA;
  }
  __syncthreads();
  const int c0 = tid >> 3, sub = tid & 7;   // 32 channels per pass, 8 x 16B = 128B runs
#pragma unroll
  for (int cl = 0; cl < 2; ++cl) {
    const int c = c0 + 32 * cl;
    const long plane = ((long)((n << 6) + c)) << 16;
#pragma unroll
    for (int i = 0; i < 4; ++i) {
      const int pst = (i * 8 + sub) << 2;
      f32x4 vbuf;
#pragma unroll
      for (int j = 0; j < 4; ++j) vbuf[j] = t[pst + j][c];
      *(f32x4*)(&out[plane + hw0 + pst]) = vbuf;
    }
  }
}

extern "C" void kernel_launch(void* const* d_in, const int* in_sizes, int n_in,
                              void* d_out, int out_size, void* d_ws, size_t ws_size,
                              hipStream_t stream) {
  (void)in_sizes; (void)n_in; (void)out_size; (void)ws_size;
  const float* x  = (const float*)d_in[0];
  const float* wq = (const float*)d_in[1];
  const float* gq = (const float*)d_in[2];
  const float* bq = (const float*)d_in[3];
  const float* wk = (const float*)d_in[4];
  const float* gk = (const float*)d_in[5];
  const float* bk = (const float*)d_in[6];
  const float* wv = (const float*)d_in[7];
  const float* gv = (const float*)d_in[8];
  const float* bv = (const float*)d_in[9];
  const float* gn = (const float*)d_in[10];
  const float* bn_ = (const float*)d_in[11];
  char* ws = (char*)d_ws;
  float* S   = (float*)(ws + OFF_SUMS);
  u16* wt    = (u16*)(ws + OFF_WT);
  float* asp = (float*)(ws + OFF_ASP);
  u16* conv  = (u16*)(ws + OFF_CONV);
  float* out = (float*)d_out;
  u16* xt  = (u16*)d_out;  // padded pre-swizzled bf16 scratch in d_out; overwritten by k6_k

  tr_k<<<4537, 256, 0, stream>>>(x, xt, wq, wk, wv, wt, S);
  conv_k<<<4096, 256, 0, stream>>>(xt, wt, conv, S);
  k3_k<<<4096, 256, 0, stream>>>(conv, S, asp, gq, bq, gk, bk, gv, bv);
  k6_k<<<4096, 256, 0, stream>>>(conv, S, asp, out, gv, bv, gn, bn_);
}